// Round 2
// baseline (534.093 us; speedup 1.0000x reference)
//
#include <hip/hip_runtime.h>
#include <hip/hip_bf16.h>
#include <math.h>

typedef __bf16 bf16;
typedef __bf16 bf16x8 __attribute__((ext_vector_type(8)));
typedef float  f32x4  __attribute__((ext_vector_type(4)));
typedef int    i32x4  __attribute__((ext_vector_type(4)));

__device__ __forceinline__ float gelu_f(float x) {
    // exact GELU: 0.5*x*(1+erf(x/sqrt(2)))
    return 0.5f * x * (1.0f + erff(x * 0.70710678118654752440f));
}

// ---------------------------------------------------------------------------
// Input-dtype detection. flag: 0 = bf16, 1 = fp32.
// ---------------------------------------------------------------------------
__global__ void detect_k(const unsigned short* __restrict__ h, int* __restrict__ flag)
{
    if (threadIdx.x == 0 && blockIdx.x == 0) {
        int cnt = 0;
        for (int i = 0; i < 256; i += 2) {
            int e = (h[i] >> 7) & 0xFF;
            cnt += (e >= 100 && e <= 140) ? 1 : 0;
        }
        *flag = (cnt >= 96) ? 0 : 1;
    }
}

// ---------------------------------------------------------------------------
// One kernel for all 7 small tensors (mask, b1, b2, g1, be1, g2, be2).
// ---------------------------------------------------------------------------
struct SmallConvArgs {
    const void* src[7];
    bf16* dst[7];
    int n[7];
};
__global__ __launch_bounds__(256) void small_convert_k(SmallConvArgs a,
                                                       const int* __restrict__ flag)
{
    const int seg = blockIdx.y;
    const int i = blockIdx.x * 256 + threadIdx.x;
    if (i >= a.n[seg]) return;
    const float v = (*flag) ? ((const float*)a.src[seg])[i]
                            : (float)((const bf16*)a.src[seg])[i];
    a.dst[seg][i] = (bf16)v;
}

// ---------------------------------------------------------------------------
// Fused convert + transpose for weights: in[R,C] (fp32 or bf16) -> outT[C,R] bf16.
// ---------------------------------------------------------------------------
__global__ __launch_bounds__(256) void conv_transpose_k(
    const void* __restrict__ in, bf16* __restrict__ outT,
    int R, int C, const int* __restrict__ flag)
{
    __shared__ bf16 tile[32][33];
    const int c0 = blockIdx.x * 32;
    const int r0 = blockIdx.y * 32;
    const int tx = threadIdx.x & 31;
    const int ty = threadIdx.x >> 5;   // 0..7
    const bool f32 = (*flag) != 0;
#pragma unroll
    for (int i = 0; i < 32; i += 8) {
        const long idx = (long)(r0 + ty + i) * C + (c0 + tx);
        const float v = f32 ? ((const float*)in)[idx] : (float)((const bf16*)in)[idx];
        tile[ty + i][tx] = (bf16)v;
    }
    __syncthreads();
#pragma unroll
    for (int i = 0; i < 32; i += 8)
        outT[(long)(c0 + ty + i) * R + (r0 + tx)] = tile[tx][ty + i];
}

// ---------------------------------------------------------------------------
// Fused convert + transpose for h: writes h_bf [B,S,D] and hT [B,D,S].
// ---------------------------------------------------------------------------
__global__ __launch_bounds__(256) void conv_transpose_h_k(
    const void* __restrict__ in, bf16* __restrict__ h_bf, bf16* __restrict__ hT,
    int S, int D, const int* __restrict__ flag)
{
    __shared__ bf16 tile[32][33];
    const long sB = (long)S * D;
    const int d0 = blockIdx.x * 32;
    const int s0 = blockIdx.y * 32;
    const int b  = blockIdx.z;
    const int tx = threadIdx.x & 31;
    const int ty = threadIdx.x >> 5;
    const bool f32 = (*flag) != 0;
#pragma unroll
    for (int i = 0; i < 32; i += 8) {
        const long idx = b * sB + (long)(s0 + ty + i) * D + (d0 + tx);
        const float v = f32 ? ((const float*)in)[idx] : (float)((const bf16*)in)[idx];
        const bf16 bv = (bf16)v;
        h_bf[idx] = bv;
        tile[ty + i][tx] = bv;
    }
    __syncthreads();
#pragma unroll
    for (int i = 0; i < 32; i += 8)
        hT[b * sB + (long)(d0 + ty + i) * S + (s0 + tx)] = tile[tx][ty + i];
}

// ---------------------------------------------------------------------------
// global_load_lds 16B: wave-uniform LDS dest + lane*16; per-lane global src.
// ---------------------------------------------------------------------------
__device__ __forceinline__ void gll16(const bf16* g, bf16* l)
{
    __builtin_amdgcn_global_load_lds(
        (const __attribute__((address_space(1))) void*)g,
        (__attribute__((address_space(3))) void*)l, 16, 0, 0);
}

// ---------------------------------------------------------------------------
// Inline-asm ds_read_b128 from a raw 32-bit LDS byte address.
// Deliberately NO "memory" clobber: keeps the read invisible to the memory
// legalizer so it cannot insert vmcnt(0) waits against outstanding
// global_load_lds prefetches (R1 post-mortem: tracked C++ LDS reads caused
// compiler drain-to-0 every phase -> 599 TF). Ordering is manual per rule
// #18: barrier -> s_waitcnt lgkmcnt(0) -> sched_barrier(0) -> MFMA.
// ---------------------------------------------------------------------------
__device__ __forceinline__ bf16x8 lds_read_b128(unsigned addr)
{
    i32x4 r;
    asm volatile("ds_read_b128 %0, %1" : "=v"(r) : "v"(addr));
    return __builtin_bit_cast(bf16x8, r);
}

#define LDS_ADDR(p) ((unsigned)(unsigned long long)(const __attribute__((address_space(3))) void*)(p))

// ---------------------------------------------------------------------------
// 128x128 NT GEMM (kept for N=1024 cases: attn out, FFN2).
// ---------------------------------------------------------------------------
template <int MODE>
__global__ __launch_bounds__(256) void gemm_nt(
    const bf16* __restrict__ A, const bf16* __restrict__ Bt,
    bf16* __restrict__ C, const bf16* __restrict__ bias,
    int M, int N, int K, float scale,
    long sA, long sB, long sC)
{
    A  += (long)blockIdx.z * sA;
    Bt += (long)blockIdx.z * sB;
    C  += (long)blockIdx.z * sC;

    const int tileM = blockIdx.y * 128;
    const int tileN = blockIdx.x * 128;

    __shared__ __align__(16) bf16 As[128 * 64];
    __shared__ __align__(16) bf16 Bs[128 * 64];

    const int t    = threadIdx.x;
    const int lane = t & 63;
    const int wave = t >> 6;
    const int wr   = wave >> 1;
    const int wc   = wave & 1;
    const int quad = lane >> 4;
    const int l16  = lane & 15;

    f32x4 acc[4][4] = {};

    auto swz = [](int row, int chunk) { return row * 64 + (((chunk + row) & 7) * 8); };

    for (int k0 = 0; k0 < K; k0 += 64) {
        bf16x8 ra[4], rb[4];
#pragma unroll
        for (int r = 0; r < 4; ++r) {
            const int e   = (r * 256 + t) * 8;
            const int row = e >> 6;
            const int col = e & 63;
            ra[r] = *(const bf16x8*)(A  + (long)(tileM + row) * K + (k0 + col));
            rb[r] = *(const bf16x8*)(Bt + (long)(tileN + row) * K + (k0 + col));
        }
#pragma unroll
        for (int r = 0; r < 4; ++r) {
            const int row = (r * 256 + t) >> 3;
            const int off = swz(row, t & 7);
            *(bf16x8*)&As[off] = ra[r];
            *(bf16x8*)&Bs[off] = rb[r];
        }
        __syncthreads();

#pragma unroll
        for (int kk = 0; kk < 64; kk += 32) {
            const int chunk = (kk >> 3) + quad;
            bf16x8 af[4], bfr[4];
#pragma unroll
            for (int i = 0; i < 4; ++i) {
                af[i]  = *(const bf16x8*)&As[swz(wr * 64 + i * 16 + l16, chunk)];
                bfr[i] = *(const bf16x8*)&Bs[swz(wc * 64 + i * 16 + l16, chunk)];
            }
#pragma unroll
            for (int mi = 0; mi < 4; ++mi)
#pragma unroll
                for (int ni = 0; ni < 4; ++ni)
                    acc[mi][ni] = __builtin_amdgcn_mfma_f32_16x16x32_bf16(
                        af[mi], bfr[ni], acc[mi][ni], 0, 0, 0);
        }
        __syncthreads();
    }

#pragma unroll
    for (int mi = 0; mi < 4; ++mi) {
        const int rbase = tileM + wr * 64 + mi * 16 + quad * 4;
#pragma unroll
        for (int ni = 0; ni < 4; ++ni) {
            const int col = tileN + wc * 64 + ni * 16 + l16;
            float bv = 0.0f;
            if (MODE >= 2) bv = (float)bias[col];
#pragma unroll
            for (int r = 0; r < 4; ++r) {
                float v = acc[mi][ni][r];
                if (MODE == 0) v *= scale;
                if (MODE >= 2) v += bv;
                if (MODE == 2) v = gelu_f(v);
                C[(long)(rbase + r) * N + col] = (bf16)v;
            }
        }
    }
}

// ---------------------------------------------------------------------------
// 256x256 NT GEMM, 8-wave, BK=64, double-buffered 128KiB LDS, deep pipeline.
// R2: LDS reads are inline-asm ds_read_b128 (invisible to the memory
// legalizer) so the counted-vmcnt pipeline survives compilation. Manual
// ordering: per phase {asm ds_reads || GLL stage -> s_barrier ->
// s_waitcnt lgkmcnt(0) -> sched_barrier(0) -> setprio(1) 16xMFMA setprio(0)
// -> sched_barrier(0) -> s_barrier}; once per K-tile: s_waitcnt vmcnt(4).
// Staging safety ledger (per iteration u, buffers cu=u&1, nx=cu^1):
//  ph0: reads A(cu) mi0-3, B(cu) ni0-1;  GLL B1(u+1)->Bs[nx] hi
//  ph1: reads B(cu) ni2-3;               GLL A1(u+1)->As[nx] hi
//  ph2: reads A(cu) mi4-7;               GLL B0(u+2)->Bs[cu] lo (freed ph1)
//  ph3: (register-resident only);        GLL A0(u+2)->As[cu] lo (freed ph2)
//  end: vmcnt(4) retires exactly tile u+1's 8 loads; leaves u+2's 4 in flight.
// All ds_read addresses are loop-invariant except the buffer bit: precomputed
// once (compile-time-indexed arrays -> registers), + (cu<<15) per read.
// Requires M%256==0, N%256==0, K%64==0.
// ---------------------------------------------------------------------------
template <int MODE>
__global__ __launch_bounds__(512, 2) void gemm_nt_256(
    const bf16* __restrict__ A, const bf16* __restrict__ Bt,
    bf16* __restrict__ C, const bf16* __restrict__ bias,
    int M, int N, int K, float scale,
    long sA, long sB, long sC)
{
    A  += (long)blockIdx.z * sA;
    Bt += (long)blockIdx.z * sB;
    C  += (long)blockIdx.z * sC;

    const int tileM = blockIdx.y * 256;
    const int tileN = blockIdx.x * 256;

    __shared__ __align__(16) bf16 As[2][256 * 64];   // 64 KiB (32 KiB per buf)
    __shared__ __align__(16) bf16 Bs[2][256 * 64];   // 64 KiB

    const int t    = threadIdx.x;
    const int lane = t & 63;
    const int wave = t >> 6;         // 0..7
    const int wr   = wave >> 2;      // 0..1 -> 128-row strip of C
    const int wc   = wave & 3;       // 0..3 -> 64-col strip of C
    const int quad = lane >> 4;
    const int l16  = lane & 15;

    // staging lane constants: GLL writes lane l at ldsbase + l*16B (linear).
    // Logical chunk c of row r must land at physical chunk (c+r)&7, so lane
    // (srow, p) fetches logical chunk (p - srow)&7 from global (rule #21).
    const int srow   = lane >> 3;                  // row within 8-row group
    const int lchunk = ((lane & 7) - srow) & 7;    // logical chunk to fetch

    const int NK = K >> 6;

    // stage one 128x64 half-tile: 2 GLL per wave (each covers 64 rows).
    auto stageHalf = [&](const bf16* src, bf16* lbuf, int rowBase, int k0) {
#pragma unroll
        for (int rnd = 0; rnd < 2; ++rnd) {
            const int r = rnd * 64 + wave * 8;     // wave-uniform row in half
            const bf16* g = src + (long)(rowBase + r + srow) * K + (k0 + lchunk * 8);
            gll16(g, lbuf + r * 64);
        }
    };

    // ---- precomputed swizzled LDS byte addresses (buffer 0) ----
    const unsigned asb = LDS_ADDR(&As[0][0]);
    const unsigned bsb = LDS_ADDR(&Bs[0][0]);
    unsigned aAddr[8][2], bAddr[4][2];
#pragma unroll
    for (int mi = 0; mi < 8; ++mi)
#pragma unroll
        for (int ks = 0; ks < 2; ++ks) {
            const int row = wr * 128 + mi * 16 + l16;
            const int ch  = ks * 4 + quad;
            aAddr[mi][ks] = asb + row * 128 + (((ch + row) & 7) * 16);
        }
#pragma unroll
    for (int ni = 0; ni < 4; ++ni)
#pragma unroll
        for (int ks = 0; ks < 2; ++ks) {
            const int row = wc * 64 + ni * 16 + l16;
            const int ch  = ks * 4 + quad;
            bAddr[ni][ks] = bsb + row * 128 + (((ch + row) & 7) * 16);
        }

    f32x4 acc[8][4] = {};

    // ---- prologue: tile0 (4 halves) + tile1 {B0, A0}; vmcnt(4) -> tile0 ready
    stageHalf(Bt, &Bs[0][0],        tileN,       0);
    stageHalf(Bt, &Bs[0][128 * 64], tileN + 128, 0);
    stageHalf(A,  &As[0][0],        tileM,       0);
    stageHalf(A,  &As[0][128 * 64], tileM + 128, 0);
    if (NK > 1) {
        stageHalf(Bt, &Bs[1][0], tileN, 64);
        stageHalf(A,  &As[1][0], tileM, 64);
        asm volatile("s_waitcnt vmcnt(4)" ::: "memory");
    } else {
        asm volatile("s_waitcnt vmcnt(0)" ::: "memory");
    }
    __builtin_amdgcn_s_barrier();

    for (int u = 0; u < NK; ++u) {
        const int cu = u & 1;
        const int nx = cu ^ 1;
        const unsigned boff = (unsigned)cu << 15;  // buffer byte offset (32 KiB)
        const int k1 = (u + 1) << 6;
        const int k2 = (u + 2) << 6;
        const bool st1 = (u + 1 < NK);
        const bool st2 = (u + 2 < NK);

        bf16x8 aF[4][2], bF[4][2];

        // ---------- phase 0: A frags mi0-3 + B frags ni0-1 (12 ds_read)
#pragma unroll
        for (int mi = 0; mi < 4; ++mi)
#pragma unroll
            for (int ks = 0; ks < 2; ++ks)
                aF[mi][ks] = lds_read_b128(aAddr[mi][ks] + boff);
#pragma unroll
        for (int ni = 0; ni < 2; ++ni)
#pragma unroll
            for (int ks = 0; ks < 2; ++ks)
                bF[ni][ks] = lds_read_b128(bAddr[ni][ks] + boff);
        if (st1) stageHalf(Bt, &Bs[nx][128 * 64], tileN + 128, k1);   // B1(u+1)
        __builtin_amdgcn_s_barrier();
        asm volatile("s_waitcnt lgkmcnt(0)" ::: "memory");
        __builtin_amdgcn_sched_barrier(0);
        __builtin_amdgcn_s_setprio(1);
#pragma unroll
        for (int mi = 0; mi < 4; ++mi)
#pragma unroll
            for (int ni = 0; ni < 2; ++ni)
#pragma unroll
                for (int ks = 0; ks < 2; ++ks)
                    acc[mi][ni] = __builtin_amdgcn_mfma_f32_16x16x32_bf16(
                        aF[mi][ks], bF[ni][ks], acc[mi][ni], 0, 0, 0);
        __builtin_amdgcn_s_setprio(0);
        __builtin_amdgcn_sched_barrier(0);
        __builtin_amdgcn_s_barrier();

        // ---------- phase 1: B frags ni2-3 (4 ds_read)
#pragma unroll
        for (int ni = 0; ni < 2; ++ni)
#pragma unroll
            for (int ks = 0; ks < 2; ++ks)
                bF[2 + ni][ks] = lds_read_b128(bAddr[2 + ni][ks] + boff);
        if (st1) stageHalf(A, &As[nx][128 * 64], tileM + 128, k1);    // A1(u+1)
        __builtin_amdgcn_s_barrier();
        asm volatile("s_waitcnt lgkmcnt(0)" ::: "memory");
        __builtin_amdgcn_sched_barrier(0);
        __builtin_amdgcn_s_setprio(1);
#pragma unroll
        for (int mi = 0; mi < 4; ++mi)
#pragma unroll
            for (int ni = 0; ni < 2; ++ni)
#pragma unroll
                for (int ks = 0; ks < 2; ++ks)
                    acc[mi][2 + ni] = __builtin_amdgcn_mfma_f32_16x16x32_bf16(
                        aF[mi][ks], bF[2 + ni][ks], acc[mi][2 + ni], 0, 0, 0);
        __builtin_amdgcn_s_setprio(0);
        __builtin_amdgcn_sched_barrier(0);
        __builtin_amdgcn_s_barrier();

        // ---------- phase 2: A frags mi4-7 (8 ds_read)
#pragma unroll
        for (int mi = 0; mi < 4; ++mi)
#pragma unroll
            for (int ks = 0; ks < 2; ++ks)
                aF[mi][ks] = lds_read_b128(aAddr[4 + mi][ks] + boff);
        if (st2) stageHalf(Bt, &Bs[cu][0], tileN, k2);                // B0(u+2)
        __builtin_amdgcn_s_barrier();
        asm volatile("s_waitcnt lgkmcnt(0)" ::: "memory");
        __builtin_amdgcn_sched_barrier(0);
        __builtin_amdgcn_s_setprio(1);
#pragma unroll
        for (int mi = 0; mi < 4; ++mi)
#pragma unroll
            for (int ni = 0; ni < 2; ++ni)
#pragma unroll
                for (int ks = 0; ks < 2; ++ks)
                    acc[4 + mi][ni] = __builtin_amdgcn_mfma_f32_16x16x32_bf16(
                        aF[mi][ks], bF[ni][ks], acc[4 + mi][ni], 0, 0, 0);
        __builtin_amdgcn_s_setprio(0);
        __builtin_amdgcn_sched_barrier(0);
        __builtin_amdgcn_s_barrier();

        // ---------- phase 3: register-resident; stage A0(u+2)
        if (st2) stageHalf(A, &As[cu][0], tileM, k2);                 // A0(u+2)
        __builtin_amdgcn_s_setprio(1);
#pragma unroll
        for (int mi = 0; mi < 4; ++mi)
#pragma unroll
            for (int ni = 0; ni < 2; ++ni)
#pragma unroll
                for (int ks = 0; ks < 2; ++ks)
                    acc[4 + mi][2 + ni] = __builtin_amdgcn_mfma_f32_16x16x32_bf16(
                        aF[mi][ks], bF[2 + ni][ks], acc[4 + mi][2 + ni], 0, 0, 0);
        __builtin_amdgcn_s_setprio(0);
        __builtin_amdgcn_sched_barrier(0);

        // ---------- end-of-iteration: counted wait, never 0 mid-loop
        if (st1) {
            if (st2) asm volatile("s_waitcnt vmcnt(4)" ::: "memory");
            else     asm volatile("s_waitcnt vmcnt(0)" ::: "memory");
            __builtin_amdgcn_s_barrier();
        }
    }

    // ---- epilogue ----
#pragma unroll
    for (int mi = 0; mi < 8; ++mi) {
        const int rbase = tileM + wr * 128 + mi * 16 + quad * 4;
#pragma unroll
        for (int ni = 0; ni < 4; ++ni) {
            const int col = tileN + wc * 64 + ni * 16 + l16;
            float bv = 0.0f;
            if (MODE >= 2) bv = (float)bias[col];
#pragma unroll
            for (int r = 0; r < 4; ++r) {
                float v = acc[mi][ni][r];
                if (MODE == 0) v *= scale;
                if (MODE >= 2) v += bv;
                if (MODE == 2) v = gelu_f(v);
                C[(long)(rbase + r) * N + col] = (bf16)v;
            }
        }
    }
}

// ---------------------------------------------------------------------------
// Row softmax with additive mask, in place, vectorized bf16x8.
// ---------------------------------------------------------------------------
__global__ __launch_bounds__(256) void softmax_k(
    bf16* __restrict__ scores, const bf16* __restrict__ mask, int S)
{
    const long rowOff = ((long)blockIdx.y * S + blockIdx.x) * S;
    bf16* row = scores + rowOff;
    const bf16* mrow = mask + (long)blockIdx.y * S;
    const int t = threadIdx.x;

    const bf16x8 r = ((const bf16x8*)row)[t];
    const bf16x8 m = ((const bf16x8*)mrow)[t];
    float v[8];
    float mx = -1e30f;
#pragma unroll
    for (int i = 0; i < 8; ++i) {
        v[i] = (float)r[i] + (float)m[i];
        mx = fmaxf(mx, v[i]);
    }
#pragma unroll
    for (int off = 32; off > 0; off >>= 1)
        mx = fmaxf(mx, __shfl_down(mx, off));
    __shared__ float redm[4];
    if ((t & 63) == 0) redm[t >> 6] = mx;
    __syncthreads();
    mx = fmaxf(fmaxf(redm[0], redm[1]), fmaxf(redm[2], redm[3]));

    float s = 0.0f;
#pragma unroll
    for (int i = 0; i < 8; ++i) { v[i] = __expf(v[i] - mx); s += v[i]; }
#pragma unroll
    for (int off = 32; off > 0; off >>= 1)
        s += __shfl_down(s, off);
    __shared__ float reds[4];
    if ((t & 63) == 0) reds[t >> 6] = s;
    __syncthreads();
    s = reds[0] + reds[1] + reds[2] + reds[3];
    const float inv = 1.0f / s;
    bf16x8 o;
#pragma unroll
    for (int i = 0; i < 8; ++i) o[i] = (bf16)(v[i] * inv);
    ((bf16x8*)row)[t] = o;
}

// ---------------------------------------------------------------------------
// Fused residual + LayerNorm -> bf16 out, vectorized bf16x8.
// ---------------------------------------------------------------------------
__global__ __launch_bounds__(128) void ln_residual_k(
    const bf16* __restrict__ x1, const bf16* __restrict__ x2,
    const bf16* __restrict__ gamma, const bf16* __restrict__ beta,
    bf16* __restrict__ out)
{
    constexpr int D = 1024;
    const long off = (long)blockIdx.x * D;
    const int t = threadIdx.x;
    const bf16x8 a = ((const bf16x8*)(x1 + off))[t];
    const bf16x8 b = ((const bf16x8*)(x2 + off))[t];
    float v[8];
    float s = 0.0f, s2 = 0.0f;
#pragma unroll
    for (int i = 0; i < 8; ++i) {
        v[i] = (float)a[i] + (float)b[i];
        s  += v[i];
        s2 += v[i] * v[i];
    }
#pragma unroll
    for (int o2 = 32; o2 > 0; o2 >>= 1) {
        s  += __shfl_down(s, o2);
        s2 += __shfl_down(s2, o2);
    }
    __shared__ float rs[2], rs2[2];
    if ((t & 63) == 0) { rs[t >> 6] = s; rs2[t >> 6] = s2; }
    __syncthreads();
    s  = rs[0] + rs[1];
    s2 = rs2[0] + rs2[1];
    const float mean = s / (float)D;
    const float var  = s2 / (float)D - mean * mean;
    const float inv  = rsqrtf(var + 1e-5f);
    const bf16x8 g  = ((const bf16x8*)gamma)[t];
    const bf16x8 be = ((const bf16x8*)beta)[t];
    bf16x8 o;
#pragma unroll
    for (int i = 0; i < 8; ++i)
        o[i] = (bf16)((v[i] - mean) * inv * (float)g[i] + (float)be[i]);
    ((bf16x8*)(out + off))[t] = o;
}

// ---------------------------------------------------------------------------
// Final residual + LayerNorm -> d_out with flag-aware store dtype.
// ---------------------------------------------------------------------------
__global__ __launch_bounds__(128) void ln_out_k(
    const bf16* __restrict__ x1, const bf16* __restrict__ x2,
    const bf16* __restrict__ gamma, const bf16* __restrict__ beta,
    void* __restrict__ outv, const int* __restrict__ flag)
{
    constexpr int D = 1024;
    const long off = (long)blockIdx.x * D;
    const int t = threadIdx.x;
    const bf16x8 a = ((const bf16x8*)(x1 + off))[t];
    const bf16x8 b = ((const bf16x8*)(x2 + off))[t];
    float v[8];
    float s = 0.0f, s2 = 0.0f;
#pragma unroll
    for (int i = 0; i < 8; ++i) {
        v[i] = (float)a[i] + (float)b[i];
        s  += v[i];
        s2 += v[i] * v[i];
    }
#pragma unroll
    for (int o2 = 32; o2 > 0; o2 >>= 1) {
        s  += __shfl_down(s, o2);
        s2 += __shfl_down(s2, o2);
    }
    __shared__ float rs[2], rs2[2];
    if ((t & 63) == 0) { rs[t >> 6] = s; rs2[t >> 6] = s2; }
    __syncthreads();
    s  = rs[0] + rs[1];
    s2 = rs2[0] + rs2[1];
    const float mean = s / (float)D;
    const float var  = s2 / (float)D - mean * mean;
    const float inv  = rsqrtf(var + 1e-5f);
    const bf16x8 g  = ((const bf16x8*)gamma)[t];
    const bf16x8 be = ((const bf16x8*)beta)[t];
    if (*flag) {
        f32x4 o1, o2v;
#pragma unroll
        for (int i = 0; i < 4; ++i) {
            o1[i]  = (v[i] - mean) * inv * (float)g[i] + (float)be[i];
            o2v[i] = (v[4 + i] - mean) * inv * (float)g[4 + i] + (float)be[4 + i];
        }
        f32x4* op = (f32x4*)((float*)outv + off);
        op[t * 2]     = o1;
        op[t * 2 + 1] = o2v;
    } else {
        bf16x8 o;
#pragma unroll
        for (int i = 0; i < 8; ++i)
            o[i] = (bf16)((v[i] - mean) * inv * (float)g[i] + (float)be[i]);
        ((bf16x8*)((bf16*)outv + off))[t] = o;
    }
}

// ---------------------------------------------------------------------------
extern "C" void kernel_launch(void* const* d_in, const int* in_sizes, int n_in,
                              void* d_out, int out_size, void* d_ws, size_t ws_size,
                              hipStream_t stream)
{
    constexpr int B = 4, S = 2048, D = 1024, F = 4096;
    constexpr long MB = 1024 * 1024;

    const void* h_raw  = d_in[0];
    const void* mk_raw = d_in[1];
    const void* w1_raw = d_in[2];
    const void* b1_raw = d_in[3];
    const void* w2_raw = d_in[4];
    const void* b2_raw = d_in[5];
    const void* g1_raw = d_in[6];
    const void* be1_raw= d_in[7];
    const void* g2_raw = d_in[8];
    const void* be2_raw= d_in[9];

    // ws layout (liveness-checked overlays), 112 MiB + small tail:
    char* ws = (char*)d_ws;
    bf16* scores = (bf16*)(ws + 0);
    bf16* gact   = (bf16*)(ws + 0);
    bf16* hT     = (bf16*)(ws + 32 * MB);
    bf16* h_bf   = (bf16*)(ws + 48 * MB);
    bf16* y1     = (bf16*)(ws + 64 * MB);
    bf16* w1T    = (bf16*)(ws + 80 * MB);
    bf16* w2T    = (bf16*)(ws + 88 * MB);
    bf16* axf    = (bf16*)(ws + 96 * MB);    // attn, later ffn
    char* sm     = ws + 112 * MB;
    int*  flag   = (int*)(sm);
    bf16* mk_bf  = (bf16*)(sm + 1024);
    bf16* b1_bf  = (bf16*)(sm + 17408 + 1024);
    bf16* b2_bf  = (bf16*)(sm + 25600 + 3072);
    bf16* g1_bf  = (bf16*)(sm + 27648 + 3072);
    bf16* be1_bf = (bf16*)(sm + 29696 + 3072);
    bf16* g2_bf  = (bf16*)(sm + 31744 + 3072);
    bf16* be2_bf = (bf16*)(sm + 33792 + 3072);

    const long SD = (long)S * D;
    const long SS = (long)S * S;

    // 1) detect input dtype (0=bf16, 1=fp32)
    detect_k<<<1, 64, 0, stream>>>((const unsigned short*)h_raw, flag);

    // 2) all 7 small tensors in one convert kernel
    SmallConvArgs sca;
    sca.src[0] = mk_raw;  sca.dst[0] = mk_bf;  sca.n[0] = B * S;
    sca.src[1] = b1_raw;  sca.dst[1] = b1_bf;  sca.n[1] = F;
    sca.src[2] = b2_raw;  sca.dst[2] = b2_bf;  sca.n[2] = D;
    sca.src[3] = g1_raw;  sca.dst[3] = g1_bf;  sca.n[3] = D;
    sca.src[4] = be1_raw; sca.dst[4] = be1_bf; sca.n[4] = D;
    sca.src[5] = g2_raw;  sca.dst[5] = g2_bf;  sca.n[5] = D;
    sca.src[6] = be2_raw; sca.dst[6] = be2_bf; sca.n[6] = D;
    small_convert_k<<<dim3((B * S) / 256, 7), 256, 0, stream>>>(sca, flag);

    // 3) h: fused convert+transpose -> h_bf [B,S,D] and hT [B,D,S]
    conv_transpose_h_k<<<dim3(D / 32, S / 32, B), 256, 0, stream>>>(
        h_raw, h_bf, hT, S, D, flag);

    // 4) w1 [D,F] -> w1T [F,D]   5) w2 [F,D] -> w2T [D,F]
    conv_transpose_k<<<dim3(F / 32, D / 32), 256, 0, stream>>>(w1_raw, w1T, D, F, flag);
    conv_transpose_k<<<dim3(D / 32, F / 32), 256, 0, stream>>>(w2_raw, w2T, F, D, flag);

    // 6) scores = h @ h^T / 32   [B, S, S]   (256^2 deep-pipeline, 256 blocks)
    gemm_nt_256<0><<<dim3(S / 256, S / 256, B), 512, 0, stream>>>(
        h_bf, h_bf, scores, nullptr, S, S, D, 0.03125f, SD, SD, SS);

    // 7) softmax rows (+mask), in place
    softmax_k<<<dim3(S, B), 256, 0, stream>>>(scores, mk_bf, S);

    // 8) attn = probs @ h (via hT)  [B, S, D]  (N=1024 -> 128^2 kernel)
    gemm_nt<1><<<dim3(D / 128, S / 128, B), 256, 0, stream>>>(
        scores, hT, axf, nullptr, S, D, S, 1.0f, SS, SD, SD);

    // 9) y1 = LN(h + attn)
    ln_residual_k<<<B * S, 128, 0, stream>>>(h_bf, axf, g1_bf, be1_bf, y1);

    // 10) gact = GELU(y1 @ w1 + b1)  [B*S, F]  (256^2 deep-pipeline, 512 blocks)
    gemm_nt_256<2><<<dim3(F / 256, (B * S) / 256, 1), 512, 0, stream>>>(
        y1, w1T, gact, b1_bf, B * S, F, D, 1.0f, 0, 0, 0);

    // 11) ffn = gact @ w2 + b2  [B*S, D]  (N=1024 -> 128^2 kernel)
    gemm_nt<3><<<dim3(D / 128, (B * S) / 128, 1), 256, 0, stream>>>(
        gact, w2T, axf, b2_bf, B * S, D, F, 1.0f, 0, 0, 0);

    // 12) out = LN(y1 + ffn) -> d_out (flag-aware output dtype)
    ln_out_k<<<B * S, 128, 0, stream>>>(y1, axf, g2_bf, be2_bf, d_out, flag);
}

// Round 3
// 507.399 us; speedup vs baseline: 1.0526x; 1.0526x over previous
//
#include <hip/hip_runtime.h>
#include <hip/hip_bf16.h>
#include <math.h>

typedef __bf16 bf16;
typedef __bf16 bf16x8 __attribute__((ext_vector_type(8)));
typedef float  f32x4  __attribute__((ext_vector_type(4)));

__device__ __forceinline__ float gelu_f(float x) {
    // exact GELU: 0.5*x*(1+erf(x/sqrt(2)))
    return 0.5f * x * (1.0f + erff(x * 0.70710678118654752440f));
}

// ---------------------------------------------------------------------------
// Input-dtype detection. flag: 0 = bf16, 1 = fp32.
// ---------------------------------------------------------------------------
__global__ void detect_k(const unsigned short* __restrict__ h, int* __restrict__ flag)
{
    if (threadIdx.x == 0 && blockIdx.x == 0) {
        int cnt = 0;
        for (int i = 0; i < 256; i += 2) {
            int e = (h[i] >> 7) & 0xFF;
            cnt += (e >= 100 && e <= 140) ? 1 : 0;
        }
        *flag = (cnt >= 96) ? 0 : 1;
    }
}

// ---------------------------------------------------------------------------
// One kernel for all 7 small tensors (mask, b1, b2, g1, be1, g2, be2).
// ---------------------------------------------------------------------------
struct SmallConvArgs {
    const void* src[7];
    bf16* dst[7];
    int n[7];
};
__global__ __launch_bounds__(256) void small_convert_k(SmallConvArgs a,
                                                       const int* __restrict__ flag)
{
    const int seg = blockIdx.y;
    const int i = blockIdx.x * 256 + threadIdx.x;
    if (i >= a.n[seg]) return;
    const float v = (*flag) ? ((const float*)a.src[seg])[i]
                            : (float)((const bf16*)a.src[seg])[i];
    a.dst[seg][i] = (bf16)v;
}

// ---------------------------------------------------------------------------
// Fused convert + transpose for weights: in[R,C] (fp32 or bf16) -> outT[C,R] bf16.
// ---------------------------------------------------------------------------
__global__ __launch_bounds__(256) void conv_transpose_k(
    const void* __restrict__ in, bf16* __restrict__ outT,
    int R, int C, const int* __restrict__ flag)
{
    __shared__ bf16 tile[32][33];
    const int c0 = blockIdx.x * 32;
    const int r0 = blockIdx.y * 32;
    const int tx = threadIdx.x & 31;
    const int ty = threadIdx.x >> 5;   // 0..7
    const bool f32 = (*flag) != 0;
#pragma unroll
    for (int i = 0; i < 32; i += 8) {
        const long idx = (long)(r0 + ty + i) * C + (c0 + tx);
        const float v = f32 ? ((const float*)in)[idx] : (float)((const bf16*)in)[idx];
        tile[ty + i][tx] = (bf16)v;
    }
    __syncthreads();
#pragma unroll
    for (int i = 0; i < 32; i += 8)
        outT[(long)(c0 + ty + i) * R + (r0 + tx)] = tile[tx][ty + i];
}

// ---------------------------------------------------------------------------
// Fused convert + transpose for h: writes h_bf [B,S,D] and hT [B,D,S].
// ---------------------------------------------------------------------------
__global__ __launch_bounds__(256) void conv_transpose_h_k(
    const void* __restrict__ in, bf16* __restrict__ h_bf, bf16* __restrict__ hT,
    int S, int D, const int* __restrict__ flag)
{
    __shared__ bf16 tile[32][33];
    const long sB = (long)S * D;
    const int d0 = blockIdx.x * 32;
    const int s0 = blockIdx.y * 32;
    const int b  = blockIdx.z;
    const int tx = threadIdx.x & 31;
    const int ty = threadIdx.x >> 5;
    const bool f32 = (*flag) != 0;
#pragma unroll
    for (int i = 0; i < 32; i += 8) {
        const long idx = b * sB + (long)(s0 + ty + i) * D + (d0 + tx);
        const float v = f32 ? ((const float*)in)[idx] : (float)((const bf16*)in)[idx];
        const bf16 bv = (bf16)v;
        h_bf[idx] = bv;
        tile[ty + i][tx] = bv;
    }
    __syncthreads();
#pragma unroll
    for (int i = 0; i < 32; i += 8)
        hT[b * sB + (long)(d0 + ty + i) * S + (s0 + tx)] = tile[tx][ty + i];
}

// ---------------------------------------------------------------------------
// global_load_lds 16B: wave-uniform LDS dest + lane*16; per-lane global src.
// ---------------------------------------------------------------------------
__device__ __forceinline__ void gll16(const bf16* g, bf16* l)
{
    __builtin_amdgcn_global_load_lds(
        (const __attribute__((address_space(1))) void*)g,
        (__attribute__((address_space(3))) void*)l, 16, 0, 0);
}

// ---------------------------------------------------------------------------
// NT GEMM: C[M,N] = A[M,K] @ Bt[N,K]^T  (row-major, bf16 in/out, fp32 acc)
// 128x128 tile, BK=64, 256 threads = 4 waves (2x2), each wave 4x4 of 16x16
// MFMA tiles. Fragment layouts (m89/m91-verified).
//
// STAGE=0 (R0-proven reg path): explicit bf16x8 register loads -> swizzled
//   LDS stores ((chunk+row)&7 rotate; conflict-free reads; 592 TF measured).
//   Compiler hoists next-tile global loads above compute (reg prefetch).
// STAGE=1 (m97 path): global_load_lds width-16 into LINEAR [128][64] LDS,
//   linear ds_reads (16-way read conflicts EXPECTED and hidden at 2-phase
//   per m252; m97 measured 874-912 TF with this exact structure), plain
//   __syncthreads (compiler inserts the vmcnt drain; that stall is included
//   in m97's 912). No inline asm, no manual waitcnt — compiler-scheduled.
// Same-run A/B: scores(GLL) vs attn(reg) have identical FLOP counts.
// MODE: 0 = scale (scores), 1 = plain, 2 = bias+GELU, 3 = bias
// ---------------------------------------------------------------------------
template <int MODE, int STAGE>
__global__ __launch_bounds__(256) void gemm_nt(
    const bf16* __restrict__ A, const bf16* __restrict__ Bt,
    bf16* __restrict__ C, const bf16* __restrict__ bias,
    int M, int N, int K, float scale,
    long sA, long sB, long sC)
{
    A  += (long)blockIdx.z * sA;
    Bt += (long)blockIdx.z * sB;
    C  += (long)blockIdx.z * sC;

    const int tileM = blockIdx.y * 128;
    const int tileN = blockIdx.x * 128;

    __shared__ __align__(16) bf16 As[128 * 64];
    __shared__ __align__(16) bf16 Bs[128 * 64];

    const int t    = threadIdx.x;
    const int lane = t & 63;
    const int wave = t >> 6;
    const int wr   = wave >> 1;      // wave row (0..1) -> 64-row strip
    const int wc   = wave & 1;       // wave col (0..1) -> 64-col strip
    const int quad = lane >> 4;      // 0..3
    const int l16  = lane & 15;

    // GLL staging lane constants (STAGE=1): each GLL covers one 1 KiB unit =
    // 8 rows x 64 cols; lane l -> row (l>>3), col (l&7)*8 within the unit.
    const int srow = lane >> 3;
    const int scol = (lane & 7) * 8;

    f32x4 acc[4][4] = {};

    // element offset of (row, chunk): linear for GLL, rotate-swizzled for reg
    auto off_rc = [](int row, int chunk) {
        if constexpr (STAGE == 1) return row * 64 + chunk * 8;
        else                      return row * 64 + (((chunk + row) & 7) * 8);
    };

    for (int k0 = 0; k0 < K; k0 += 64) {
        if constexpr (STAGE == 1) {
            // ---- m97-style staging: 8 GLL16/thread (4 A-units + 4 B-units)
#pragma unroll
            for (int r2 = 0; r2 < 4; ++r2) {
                const int unit = wave * 4 + r2;          // 0..15, wave-uniform
                const int row  = unit * 8 + srow;
                gll16(A  + (long)(tileM + row) * K + (k0 + scol), As + unit * 512);
                gll16(Bt + (long)(tileN + row) * K + (k0 + scol), Bs + unit * 512);
            }
            __syncthreads();
        } else {
            // ---- R0-proven reg staging with rotate swizzle ----
            bf16x8 ra[4], rb[4];
#pragma unroll
            for (int r = 0; r < 4; ++r) {
                const int e   = (r * 256 + t) * 8;   // element index in tile
                const int row = e >> 6;              // tile row (64 cols)
                const int col = e & 63;
                ra[r] = *(const bf16x8*)(A  + (long)(tileM + row) * K + (k0 + col));
                rb[r] = *(const bf16x8*)(Bt + (long)(tileN + row) * K + (k0 + col));
            }
#pragma unroll
            for (int r = 0; r < 4; ++r) {
                const int row = (r * 256 + t) >> 3;  // e/64
                const int off = off_rc(row, t & 7);
                *(bf16x8*)&As[off] = ra[r];
                *(bf16x8*)&Bs[off] = rb[r];
            }
            __syncthreads();
        }

        // ---- compute: 2 MFMA K-steps of 32 ----
#pragma unroll
        for (int kk = 0; kk < 64; kk += 32) {
            const int chunk = (kk >> 3) + quad;   // logical 16B chunk index
            bf16x8 af[4], bfr[4];
#pragma unroll
            for (int i = 0; i < 4; ++i) {
                af[i]  = *(const bf16x8*)&As[off_rc(wr * 64 + i * 16 + l16, chunk)];
                bfr[i] = *(const bf16x8*)&Bs[off_rc(wc * 64 + i * 16 + l16, chunk)];
            }
#pragma unroll
            for (int mi = 0; mi < 4; ++mi)
#pragma unroll
                for (int ni = 0; ni < 4; ++ni)
                    acc[mi][ni] = __builtin_amdgcn_mfma_f32_16x16x32_bf16(
                        af[mi], bfr[ni], acc[mi][ni], 0, 0, 0);
        }
        __syncthreads();
    }

    // ---- epilogue ----
#pragma unroll
    for (int mi = 0; mi < 4; ++mi) {
        const int rbase = tileM + wr * 64 + mi * 16 + quad * 4;
#pragma unroll
        for (int ni = 0; ni < 4; ++ni) {
            const int col = tileN + wc * 64 + ni * 16 + l16;
            float bv = 0.0f;
            if (MODE >= 2) bv = (float)bias[col];
#pragma unroll
            for (int r = 0; r < 4; ++r) {
                float v = acc[mi][ni][r];
                if (MODE == 0) v *= scale;
                if (MODE >= 2) v += bv;
                if (MODE == 2) v = gelu_f(v);
                C[(long)(rbase + r) * N + col] = (bf16)v;
            }
        }
    }
}

// ---------------------------------------------------------------------------
// Row softmax with additive mask, in place, vectorized bf16x8.
// One 256-thread block per row; S = 2048 (one bf16x8 per thread).
// ---------------------------------------------------------------------------
__global__ __launch_bounds__(256) void softmax_k(
    bf16* __restrict__ scores, const bf16* __restrict__ mask, int S)
{
    const long rowOff = ((long)blockIdx.y * S + blockIdx.x) * S;
    bf16* row = scores + rowOff;
    const bf16* mrow = mask + (long)blockIdx.y * S;
    const int t = threadIdx.x;

    const bf16x8 r = ((const bf16x8*)row)[t];
    const bf16x8 m = ((const bf16x8*)mrow)[t];
    float v[8];
    float mx = -1e30f;
#pragma unroll
    for (int i = 0; i < 8; ++i) {
        v[i] = (float)r[i] + (float)m[i];
        mx = fmaxf(mx, v[i]);
    }
#pragma unroll
    for (int off = 32; off > 0; off >>= 1)
        mx = fmaxf(mx, __shfl_down(mx, off));
    __shared__ float redm[4];
    if ((t & 63) == 0) redm[t >> 6] = mx;
    __syncthreads();
    mx = fmaxf(fmaxf(redm[0], redm[1]), fmaxf(redm[2], redm[3]));

    float s = 0.0f;
#pragma unroll
    for (int i = 0; i < 8; ++i) { v[i] = __expf(v[i] - mx); s += v[i]; }
#pragma unroll
    for (int off = 32; off > 0; off >>= 1)
        s += __shfl_down(s, off);
    __shared__ float reds[4];
    if ((t & 63) == 0) reds[t >> 6] = s;
    __syncthreads();
    s = reds[0] + reds[1] + reds[2] + reds[3];
    const float inv = 1.0f / s;
    bf16x8 o;
#pragma unroll
    for (int i = 0; i < 8; ++i) o[i] = (bf16)(v[i] * inv);
    ((bf16x8*)row)[t] = o;
}

// ---------------------------------------------------------------------------
// Fused residual + LayerNorm -> bf16 out, vectorized bf16x8.
// ---------------------------------------------------------------------------
__global__ __launch_bounds__(128) void ln_residual_k(
    const bf16* __restrict__ x1, const bf16* __restrict__ x2,
    const bf16* __restrict__ gamma, const bf16* __restrict__ beta,
    bf16* __restrict__ out)
{
    constexpr int D = 1024;
    const long off = (long)blockIdx.x * D;
    const int t = threadIdx.x;
    const bf16x8 a = ((const bf16x8*)(x1 + off))[t];
    const bf16x8 b = ((const bf16x8*)(x2 + off))[t];
    float v[8];
    float s = 0.0f, s2 = 0.0f;
#pragma unroll
    for (int i = 0; i < 8; ++i) {
        v[i] = (float)a[i] + (float)b[i];
        s  += v[i];
        s2 += v[i] * v[i];
    }
#pragma unroll
    for (int o2 = 32; o2 > 0; o2 >>= 1) {
        s  += __shfl_down(s, o2);
        s2 += __shfl_down(s2, o2);
    }
    __shared__ float rs[2], rs2[2];
    if ((t & 63) == 0) { rs[t >> 6] = s; rs2[t >> 6] = s2; }
    __syncthreads();
    s  = rs[0] + rs[1];
    s2 = rs2[0] + rs2[1];
    const float mean = s / (float)D;
    const float var  = s2 / (float)D - mean * mean;
    const float inv  = rsqrtf(var + 1e-5f);
    const bf16x8 g  = ((const bf16x8*)gamma)[t];
    const bf16x8 be = ((const bf16x8*)beta)[t];
    bf16x8 o;
#pragma unroll
    for (int i = 0; i < 8; ++i)
        o[i] = (bf16)((v[i] - mean) * inv * (float)g[i] + (float)be[i]);
    ((bf16x8*)(out + off))[t] = o;
}

// ---------------------------------------------------------------------------
// Final residual + LayerNorm -> d_out with flag-aware store dtype.
// ---------------------------------------------------------------------------
__global__ __launch_bounds__(128) void ln_out_k(
    const bf16* __restrict__ x1, const bf16* __restrict__ x2,
    const bf16* __restrict__ gamma, const bf16* __restrict__ beta,
    void* __restrict__ outv, const int* __restrict__ flag)
{
    constexpr int D = 1024;
    const long off = (long)blockIdx.x * D;
    const int t = threadIdx.x;
    const bf16x8 a = ((const bf16x8*)(x1 + off))[t];
    const bf16x8 b = ((const bf16x8*)(x2 + off))[t];
    float v[8];
    float s = 0.0f, s2 = 0.0f;
#pragma unroll
    for (int i = 0; i < 8; ++i) {
        v[i] = (float)a[i] + (float)b[i];
        s  += v[i];
        s2 += v[i] * v[i];
    }
#pragma unroll
    for (int o2 = 32; o2 > 0; o2 >>= 1) {
        s  += __shfl_down(s, o2);
        s2 += __shfl_down(s2, o2);
    }
    __shared__ float rs[2], rs2[2];
    if ((t & 63) == 0) { rs[t >> 6] = s; rs2[t >> 6] = s2; }
    __syncthreads();
    s  = rs[0] + rs[1];
    s2 = rs2[0] + rs2[1];
    const float mean = s / (float)D;
    const float var  = s2 / (float)D - mean * mean;
    const float inv  = rsqrtf(var + 1e-5f);
    const bf16x8 g  = ((const bf16x8*)gamma)[t];
    const bf16x8 be = ((const bf16x8*)beta)[t];
    if (*flag) {
        f32x4 o1, o2v;
#pragma unroll
        for (int i = 0; i < 4; ++i) {
            o1[i]  = (v[i] - mean) * inv * (float)g[i] + (float)be[i];
            o2v[i] = (v[4 + i] - mean) * inv * (float)g[4 + i] + (float)be[4 + i];
        }
        f32x4* op = (f32x4*)((float*)outv + off);
        op[t * 2]     = o1;
        op[t * 2 + 1] = o2v;
    } else {
        bf16x8 o;
#pragma unroll
        for (int i = 0; i < 8; ++i)
            o[i] = (bf16)((v[i] - mean) * inv * (float)g[i] + (float)be[i]);
        ((bf16x8*)((bf16*)outv + off))[t] = o;
    }
}

// ---------------------------------------------------------------------------
extern "C" void kernel_launch(void* const* d_in, const int* in_sizes, int n_in,
                              void* d_out, int out_size, void* d_ws, size_t ws_size,
                              hipStream_t stream)
{
    constexpr int B = 4, S = 2048, D = 1024, F = 4096;
    constexpr long MB = 1024 * 1024;

    const void* h_raw  = d_in[0];
    const void* mk_raw = d_in[1];
    const void* w1_raw = d_in[2];
    const void* b1_raw = d_in[3];
    const void* w2_raw = d_in[4];
    const void* b2_raw = d_in[5];
    const void* g1_raw = d_in[6];
    const void* be1_raw= d_in[7];
    const void* g2_raw = d_in[8];
    const void* be2_raw= d_in[9];

    // ws layout (liveness-checked overlays), 112 MiB + small tail:
    char* ws = (char*)d_ws;
    bf16* scores = (bf16*)(ws + 0);
    bf16* gact   = (bf16*)(ws + 0);
    bf16* hT     = (bf16*)(ws + 32 * MB);
    bf16* h_bf   = (bf16*)(ws + 48 * MB);
    bf16* y1     = (bf16*)(ws + 64 * MB);
    bf16* w1T    = (bf16*)(ws + 80 * MB);
    bf16* w2T    = (bf16*)(ws + 88 * MB);
    bf16* axf    = (bf16*)(ws + 96 * MB);    // attn, later ffn
    char* sm     = ws + 112 * MB;
    int*  flag   = (int*)(sm);
    bf16* mk_bf  = (bf16*)(sm + 1024);
    bf16* b1_bf  = (bf16*)(sm + 17408 + 1024);
    bf16* b2_bf  = (bf16*)(sm + 25600 + 3072);
    bf16* g1_bf  = (bf16*)(sm + 27648 + 3072);
    bf16* be1_bf = (bf16*)(sm + 29696 + 3072);
    bf16* g2_bf  = (bf16*)(sm + 31744 + 3072);
    bf16* be2_bf = (bf16*)(sm + 33792 + 3072);

    const long SD = (long)S * D;
    const long SS = (long)S * S;

    // 1) detect input dtype (0=bf16, 1=fp32)
    detect_k<<<1, 64, 0, stream>>>((const unsigned short*)h_raw, flag);

    // 2) all 7 small tensors in one convert kernel
    SmallConvArgs sca;
    sca.src[0] = mk_raw;  sca.dst[0] = mk_bf;  sca.n[0] = B * S;
    sca.src[1] = b1_raw;  sca.dst[1] = b1_bf;  sca.n[1] = F;
    sca.src[2] = b2_raw;  sca.dst[2] = b2_bf;  sca.n[2] = D;
    sca.src[3] = g1_raw;  sca.dst[3] = g1_bf;  sca.n[3] = D;
    sca.src[4] = be1_raw; sca.dst[4] = be1_bf; sca.n[4] = D;
    sca.src[5] = g2_raw;  sca.dst[5] = g2_bf;  sca.n[5] = D;
    sca.src[6] = be2_raw; sca.dst[6] = be2_bf; sca.n[6] = D;
    small_convert_k<<<dim3((B * S) / 256, 7), 256, 0, stream>>>(sca, flag);

    // 3) h: fused convert+transpose -> h_bf [B,S,D] and hT [B,D,S]
    conv_transpose_h_k<<<dim3(D / 32, S / 32, B), 256, 0, stream>>>(
        h_raw, h_bf, hT, S, D, flag);

    // 4) w1 [D,F] -> w1T [F,D]   5) w2 [F,D] -> w2T [D,F]
    conv_transpose_k<<<dim3(F / 32, D / 32), 256, 0, stream>>>(w1_raw, w1T, D, F, flag);
    conv_transpose_k<<<dim3(D / 32, F / 32), 256, 0, stream>>>(w2_raw, w2T, F, D, flag);

    // 6) scores = h @ h^T / 32   [B, S, S]   (GLL variant)
    gemm_nt<0, 1><<<dim3(S / 128, S / 128, B), 256, 0, stream>>>(
        h_bf, h_bf, scores, nullptr, S, S, D, 0.03125f, SD, SD, SS);

    // 7) softmax rows (+mask), in place
    softmax_k<<<dim3(S, B), 256, 0, stream>>>(scores, mk_bf, S);

    // 8) attn = probs @ h (via hT)  [B, S, D]   (reg variant = A/B control,
    //    same FLOP count as scores GEMM)
    gemm_nt<1, 0><<<dim3(D / 128, S / 128, B), 256, 0, stream>>>(
        scores, hT, axf, nullptr, S, D, S, 1.0f, SS, SD, SD);

    // 9) y1 = LN(h + attn)
    ln_residual_k<<<B * S, 128, 0, stream>>>(h_bf, axf, g1_bf, be1_bf, y1);

    // 10) gact = GELU(y1 @ w1 + b1)  [B*S, F]   (GLL variant)
    gemm_nt<2, 1><<<dim3(F / 128, (B * S) / 128, 1), 256, 0, stream>>>(
        y1, w1T, gact, b1_bf, B * S, F, D, 1.0f, 0, 0, 0);

    // 11) ffn = gact @ w2 + b2  [B*S, D]   (GLL variant)
    gemm_nt<3, 1><<<dim3(D / 128, (B * S) / 128, 1), 256, 0, stream>>>(
        gact, w2T, axf, b2_bf, B * S, D, F, 1.0f, 0, 0, 0);

    // 12) out = LN(y1 + ffn) -> d_out (flag-aware output dtype)
    ln_out_k<<<B * S, 128, 0, stream>>>(y1, axf, g2_bf, be2_bf, d_out, flag);
}

// Round 5
// 491.770 us; speedup vs baseline: 1.0861x; 1.0318x over previous
//
#include <hip/hip_runtime.h>
#include <hip/hip_bf16.h>
#include <math.h>

typedef __bf16 bf16;
typedef __bf16 bf16x8 __attribute__((ext_vector_type(8)));
typedef float  f32x4  __attribute__((ext_vector_type(4)));

__device__ __forceinline__ float gelu_f(float x) {
    // exact GELU: 0.5*x*(1+erf(x/sqrt(2)))
    return 0.5f * x * (1.0f + erff(x * 0.70710678118654752440f));
}

// ---------------------------------------------------------------------------
// Input-dtype detection. flag: 0 = bf16, 1 = fp32.
// ---------------------------------------------------------------------------
__global__ void detect_k(const unsigned short* __restrict__ h, int* __restrict__ flag)
{
    if (threadIdx.x == 0 && blockIdx.x == 0) {
        int cnt = 0;
        for (int i = 0; i < 256; i += 2) {
            int e = (h[i] >> 7) & 0xFF;
            cnt += (e >= 100 && e <= 140) ? 1 : 0;
        }
        *flag = (cnt >= 96) ? 0 : 1;
    }
}

// ---------------------------------------------------------------------------
// One kernel for all 7 small tensors (mask, b1, b2, g1, be1, g2, be2).
// ---------------------------------------------------------------------------
struct SmallConvArgs {
    const void* src[7];
    bf16* dst[7];
    int n[7];
};
__global__ __launch_bounds__(256) void small_convert_k(SmallConvArgs a,
                                                       const int* __restrict__ flag)
{
    const int seg = blockIdx.y;
    const int i = blockIdx.x * 256 + threadIdx.x;
    if (i >= a.n[seg]) return;
    const float v = (*flag) ? ((const float*)a.src[seg])[i]
                            : (float)((const bf16*)a.src[seg])[i];
    a.dst[seg][i] = (bf16)v;
}

// ---------------------------------------------------------------------------
// Fused convert + transpose for weights: in[R,C] (fp32 or bf16) -> outT[C,R] bf16.
// ---------------------------------------------------------------------------
__global__ __launch_bounds__(256) void conv_transpose_k(
    const void* __restrict__ in, bf16* __restrict__ outT,
    int R, int C, const int* __restrict__ flag)
{
    __shared__ bf16 tile[32][33];
    const int c0 = blockIdx.x * 32;
    const int r0 = blockIdx.y * 32;
    const int tx = threadIdx.x & 31;
    const int ty = threadIdx.x >> 5;   // 0..7
    const bool f32 = (*flag) != 0;
#pragma unroll
    for (int i = 0; i < 32; i += 8) {
        const long idx = (long)(r0 + ty + i) * C + (c0 + tx);
        const float v = f32 ? ((const float*)in)[idx] : (float)((const bf16*)in)[idx];
        tile[ty + i][tx] = (bf16)v;
    }
    __syncthreads();
#pragma unroll
    for (int i = 0; i < 32; i += 8)
        outT[(long)(c0 + ty + i) * R + (r0 + tx)] = tile[tx][ty + i];
}

// ---------------------------------------------------------------------------
// Fused convert + transpose for h: writes h_bf [B,S,D] and hT [B,D,S].
// ---------------------------------------------------------------------------
__global__ __launch_bounds__(256) void conv_transpose_h_k(
    const void* __restrict__ in, bf16* __restrict__ h_bf, bf16* __restrict__ hT,
    int S, int D, const int* __restrict__ flag)
{
    __shared__ bf16 tile[32][33];
    const long sB = (long)S * D;
    const int d0 = blockIdx.x * 32;
    const int s0 = blockIdx.y * 32;
    const int b  = blockIdx.z;
    const int tx = threadIdx.x & 31;
    const int ty = threadIdx.x >> 5;
    const bool f32 = (*flag) != 0;
#pragma unroll
    for (int i = 0; i < 32; i += 8) {
        const long idx = b * sB + (long)(s0 + ty + i) * D + (d0 + tx);
        const float v = f32 ? ((const float*)in)[idx] : (float)((const bf16*)in)[idx];
        const bf16 bv = (bf16)v;
        h_bf[idx] = bv;
        tile[ty + i][tx] = bv;
    }
    __syncthreads();
#pragma unroll
    for (int i = 0; i < 32; i += 8)
        hT[b * sB + (long)(d0 + ty + i) * S + (s0 + tx)] = tile[tx][ty + i];
}

// ---------------------------------------------------------------------------
// global_load_lds 16B: wave-uniform LDS dest + lane*16; per-lane global src.
// ---------------------------------------------------------------------------
__device__ __forceinline__ void gll16(const bf16* g, bf16* l)
{
    __builtin_amdgcn_global_load_lds(
        (const __attribute__((address_space(1))) void*)g,
        (__attribute__((address_space(3))) void*)l, 16, 0, 0);
}

// ---------------------------------------------------------------------------
// NT GEMM: C[M,N] = A[M,K] @ Bt[N,K]^T  (row-major, bf16 in/out, fp32 acc)
// 128x128 tile, BK=64, 256 threads = 4 waves (2x2), each wave 4x4 of 16x16
// MFMA tiles. Fragment layouts (m89/m91-verified). LDS layout is ALWAYS the
// (chunk+row)&7 rotate swizzle -> conflict-free ds_read_b128 fragment reads
// (R0/R3 A/B: un-swizzled = 2.5e7 conflict-cycles = +27% time).
//
// STAGE=0 (reg path, R0-proven 592 TF): bf16x8 register loads -> swizzled
//   LDS stores. Costs VALU (57% busy) for addr calc + ds_write.
// STAGE=1 (R4: GLL + source-pre-swizzle, rule #21): global_load_lds writes
//   LDS LINEARLY (lane*16B); we pre-permute the per-lane GLOBAL address so
//   data lands at the swizzled layout: lane l in an 8-row unit has physical
//   chunk p=l&7, row srow=l>>3, and must fetch logical chunk (p-srow)&7.
//   Same mapping verified-in-run by the R1/R2 256^2 kernel (passed twice).
//   Global read stays coalesced (each row's 128B block fully covered, lane
//   permutation within 128B segments doesn't split transactions).
//   Removes staging VALU (R3: 57->43%) AND conflicts (R0: 2.5e7->0).
// Same-run A/B: scores(STAGE=1) vs attn(STAGE=0), identical FLOP counts.
// MODE: 0 = scale (scores), 1 = plain, 2 = bias+GELU, 3 = bias
// ---------------------------------------------------------------------------
template <int MODE, int STAGE>
__global__ __launch_bounds__(256) void gemm_nt(
    const bf16* __restrict__ A, const bf16* __restrict__ Bt,
    bf16* __restrict__ C, const bf16* __restrict__ bias,
    int M, int N, int K, float scale,
    long sA, long sB, long sC)
{
    A  += (long)blockIdx.z * sA;
    Bt += (long)blockIdx.z * sB;
    C  += (long)blockIdx.z * sC;

    const int tileM = blockIdx.y * 128;
    const int tileN = blockIdx.x * 128;

    __shared__ __align__(16) bf16 As[128 * 64];
    __shared__ __align__(16) bf16 Bs[128 * 64];

    const int t    = threadIdx.x;
    const int lane = t & 63;
    const int wave = t >> 6;
    const int wr   = wave >> 1;      // wave row (0..1) -> 64-row strip
    const int wc   = wave & 1;       // wave col (0..1) -> 64-col strip
    const int quad = lane >> 4;      // 0..3
    const int l16  = lane & 15;

    // STAGE=1 lane constants: unit = 8 rows x 64 cols = 1 KiB per GLL.
    // lane l -> LDS physical (row srow, chunk l&7); fetch logical chunk
    // (p - srow)&7 so the landed layout matches the read-side swizzle.
    const int srow   = lane >> 3;
    const int lchunk = ((lane & 7) - srow) & 7;

    f32x4 acc[4][4] = {};

    // swizzled element offset of (row, chunk): row*64 + ((chunk+row)&7)*8
    auto swz = [](int row, int chunk) { return row * 64 + (((chunk + row) & 7) * 8); };

    for (int k0 = 0; k0 < K; k0 += 64) {
        if constexpr (STAGE == 1) {
            // ---- GLL staging, source pre-swizzled: 8 GLL16/thread ----
#pragma unroll
            for (int r2 = 0; r2 < 4; ++r2) {
                const int unit = wave * 4 + r2;          // 0..15, wave-uniform
                const int row  = unit * 8 + srow;        // row&7 == srow
                const int col  = lchunk * 8;
                gll16(A  + (long)(tileM + row) * K + (k0 + col), As + unit * 512);
                gll16(Bt + (long)(tileN + row) * K + (k0 + col), Bs + unit * 512);
            }
            __syncthreads();
        } else {
            // ---- reg staging with rotate swizzle (R0-proven) ----
            bf16x8 ra[4], rb[4];
#pragma unroll
            for (int r = 0; r < 4; ++r) {
                const int e   = (r * 256 + t) * 8;   // element index in tile
                const int row = e >> 6;              // tile row (64 cols)
                const int col = e & 63;
                ra[r] = *(const bf16x8*)(A  + (long)(tileM + row) * K + (k0 + col));
                rb[r] = *(const bf16x8*)(Bt + (long)(tileN + row) * K + (k0 + col));
            }
#pragma unroll
            for (int r = 0; r < 4; ++r) {
                const int row = (r * 256 + t) >> 3;  // e/64
                const int off = swz(row, t & 7);
                *(bf16x8*)&As[off] = ra[r];
                *(bf16x8*)&Bs[off] = rb[r];
            }
            __syncthreads();
        }

        // ---- compute: 2 MFMA K-steps of 32 ----
#pragma unroll
        for (int kk = 0; kk < 64; kk += 32) {
            const int chunk = (kk >> 3) + quad;   // logical 16B chunk index
            bf16x8 af[4], bfr[4];
#pragma unroll
            for (int i = 0; i < 4; ++i) {
                af[i]  = *(const bf16x8*)&As[swz(wr * 64 + i * 16 + l16, chunk)];
                bfr[i] = *(const bf16x8*)&Bs[swz(wc * 64 + i * 16 + l16, chunk)];
            }
#pragma unroll
            for (int mi = 0; mi < 4; ++mi)
#pragma unroll
                for (int ni = 0; ni < 4; ++ni)
                    acc[mi][ni] = __builtin_amdgcn_mfma_f32_16x16x32_bf16(
                        af[mi], bfr[ni], acc[mi][ni], 0, 0, 0);
        }
        __syncthreads();
    }

    // ---- epilogue ----
#pragma unroll
    for (int mi = 0; mi < 4; ++mi) {
        const int rbase = tileM + wr * 64 + mi * 16 + quad * 4;
#pragma unroll
        for (int ni = 0; ni < 4; ++ni) {
            const int col = tileN + wc * 64 + ni * 16 + l16;
            float bv = 0.0f;
            if (MODE >= 2) bv = (float)bias[col];
#pragma unroll
            for (int r = 0; r < 4; ++r) {
                float v = acc[mi][ni][r];
                if (MODE == 0) v *= scale;
                if (MODE >= 2) v += bv;
                if (MODE == 2) v = gelu_f(v);
                C[(long)(rbase + r) * N + col] = (bf16)v;
            }
        }
    }
}

// ---------------------------------------------------------------------------
// Row softmax with additive mask, in place, vectorized bf16x8.
// One 256-thread block per row; S = 2048 (one bf16x8 per thread).
// ---------------------------------------------------------------------------
__global__ __launch_bounds__(256) void softmax_k(
    bf16* __restrict__ scores, const bf16* __restrict__ mask, int S)
{
    const long rowOff = ((long)blockIdx.y * S + blockIdx.x) * S;
    bf16* row = scores + rowOff;
    const bf16* mrow = mask + (long)blockIdx.y * S;
    const int t = threadIdx.x;

    const bf16x8 r = ((const bf16x8*)row)[t];
    const bf16x8 m = ((const bf16x8*)mrow)[t];
    float v[8];
    float mx = -1e30f;
#pragma unroll
    for (int i = 0; i < 8; ++i) {
        v[i] = (float)r[i] + (float)m[i];
        mx = fmaxf(mx, v[i]);
    }
#pragma unroll
    for (int off = 32; off > 0; off >>= 1)
        mx = fmaxf(mx, __shfl_down(mx, off));
    __shared__ float redm[4];
    if ((t & 63) == 0) redm[t >> 6] = mx;
    __syncthreads();
    mx = fmaxf(fmaxf(redm[0], redm[1]), fmaxf(redm[2], redm[3]));

    float s = 0.0f;
#pragma unroll
    for (int i = 0; i < 8; ++i) { v[i] = __expf(v[i] - mx); s += v[i]; }
#pragma unroll
    for (int off = 32; off > 0; off >>= 1)
        s += __shfl_down(s, off);
    __shared__ float reds[4];
    if ((t & 63) == 0) reds[t >> 6] = s;
    __syncthreads();
    s = reds[0] + reds[1] + reds[2] + reds[3];
    const float inv = 1.0f / s;
    bf16x8 o;
#pragma unroll
    for (int i = 0; i < 8; ++i) o[i] = (bf16)(v[i] * inv);
    ((bf16x8*)row)[t] = o;
}

// ---------------------------------------------------------------------------
// Fused residual + LayerNorm -> bf16 out, vectorized bf16x8.
// ---------------------------------------------------------------------------
__global__ __launch_bounds__(128) void ln_residual_k(
    const bf16* __restrict__ x1, const bf16* __restrict__ x2,
    const bf16* __restrict__ gamma, const bf16* __restrict__ beta,
    bf16* __restrict__ out)
{
    constexpr int D = 1024;
    const long off = (long)blockIdx.x * D;
    const int t = threadIdx.x;
    const bf16x8 a = ((const bf16x8*)(x1 + off))[t];
    const bf16x8 b = ((const bf16x8*)(x2 + off))[t];
    float v[8];
    float s = 0.0f, s2 = 0.0f;
#pragma unroll
    for (int i = 0; i < 8; ++i) {
        v[i] = (float)a[i] + (float)b[i];
        s  += v[i];
        s2 += v[i] * v[i];
    }
#pragma unroll
    for (int o2 = 32; o2 > 0; o2 >>= 1) {
        s  += __shfl_down(s, o2);
        s2 += __shfl_down(s2, o2);
    }
    __shared__ float rs[2], rs2[2];
    if ((t & 63) == 0) { rs[t >> 6] = s; rs2[t >> 6] = s2; }
    __syncthreads();
    s  = rs[0] + rs[1];
    s2 = rs2[0] + rs2[1];
    const float mean = s / (float)D;
    const float var  = s2 / (float)D - mean * mean;
    const float inv  = rsqrtf(var + 1e-5f);
    const bf16x8 g  = ((const bf16x8*)gamma)[t];
    const bf16x8 be = ((const bf16x8*)beta)[t];
    bf16x8 o;
#pragma unroll
    for (int i = 0; i < 8; ++i)
        o[i] = (bf16)((v[i] - mean) * inv * (float)g[i] + (float)be[i]);
    ((bf16x8*)(out + off))[t] = o;
}

// ---------------------------------------------------------------------------
// Final residual + LayerNorm -> d_out with flag-aware store dtype.
// ---------------------------------------------------------------------------
__global__ __launch_bounds__(128) void ln_out_k(
    const bf16* __restrict__ x1, const bf16* __restrict__ x2,
    const bf16* __restrict__ gamma, const bf16* __restrict__ beta,
    void* __restrict__ outv, const int* __restrict__ flag)
{
    constexpr int D = 1024;
    const long off = (long)blockIdx.x * D;
    const int t = threadIdx.x;
    const bf16x8 a = ((const bf16x8*)(x1 + off))[t];
    const bf16x8 b = ((const bf16x8*)(x2 + off))[t];
    float v[8];
    float s = 0.0f, s2 = 0.0f;
#pragma unroll
    for (int i = 0; i < 8; ++i) {
        v[i] = (float)a[i] + (float)b[i];
        s  += v[i];
        s2 += v[i] * v[i];
    }
#pragma unroll
    for (int o2 = 32; o2 > 0; o2 >>= 1) {
        s  += __shfl_down(s, o2);
        s2 += __shfl_down(s2, o2);
    }
    __shared__ float rs[2], rs2[2];
    if ((t & 63) == 0) { rs[t >> 6] = s; rs2[t >> 6] = s2; }
    __syncthreads();
    s  = rs[0] + rs[1];
    s2 = rs2[0] + rs2[1];
    const float mean = s / (float)D;
    const float var  = s2 / (float)D - mean * mean;
    const float inv  = rsqrtf(var + 1e-5f);
    const bf16x8 g  = ((const bf16x8*)gamma)[t];
    const bf16x8 be = ((const bf16x8*)beta)[t];
    if (*flag) {
        f32x4 o1, o2v;
#pragma unroll
        for (int i = 0; i < 4; ++i) {
            o1[i]  = (v[i] - mean) * inv * (float)g[i] + (float)be[i];
            o2v[i] = (v[4 + i] - mean) * inv * (float)g[4 + i] + (float)be[4 + i];
        }
        f32x4* op = (f32x4*)((float*)outv + off);
        op[t * 2]     = o1;
        op[t * 2 + 1] = o2v;
    } else {
        bf16x8 o;
#pragma unroll
        for (int i = 0; i < 8; ++i)
            o[i] = (bf16)((v[i] - mean) * inv * (float)g[i] + (float)be[i]);
        ((bf16x8*)((bf16*)outv + off))[t] = o;
    }
}

// ---------------------------------------------------------------------------
extern "C" void kernel_launch(void* const* d_in, const int* in_sizes, int n_in,
                              void* d_out, int out_size, void* d_ws, size_t ws_size,
                              hipStream_t stream)
{
    constexpr int B = 4, S = 2048, D = 1024, F = 4096;
    constexpr long MB = 1024 * 1024;

    const void* h_raw  = d_in[0];
    const void* mk_raw = d_in[1];
    const void* w1_raw = d_in[2];
    const void* b1_raw = d_in[3];
    const void* w2_raw = d_in[4];
    const void* b2_raw = d_in[5];
    const void* g1_raw = d_in[6];
    const void* be1_raw= d_in[7];
    const void* g2_raw = d_in[8];
    const void* be2_raw= d_in[9];

    // ws layout (liveness-checked overlays), 112 MiB + small tail:
    char* ws = (char*)d_ws;
    bf16* scores = (bf16*)(ws + 0);
    bf16* gact   = (bf16*)(ws + 0);
    bf16* hT     = (bf16*)(ws + 32 * MB);
    bf16* h_bf   = (bf16*)(ws + 48 * MB);
    bf16* y1     = (bf16*)(ws + 64 * MB);
    bf16* w1T    = (bf16*)(ws + 80 * MB);
    bf16* w2T    = (bf16*)(ws + 88 * MB);
    bf16* axf    = (bf16*)(ws + 96 * MB);    // attn, later ffn
    char* sm     = ws + 112 * MB;
    int*  flag   = (int*)(sm);
    bf16* mk_bf  = (bf16*)(sm + 1024);
    bf16* b1_bf  = (bf16*)(sm + 17408 + 1024);
    bf16* b2_bf  = (bf16*)(sm + 25600 + 3072);
    bf16* g1_bf  = (bf16*)(sm + 27648 + 3072);
    bf16* be1_bf = (bf16*)(sm + 29696 + 3072);
    bf16* g2_bf  = (bf16*)(sm + 31744 + 3072);
    bf16* be2_bf = (bf16*)(sm + 33792 + 3072);

    const long SD = (long)S * D;
    const long SS = (long)S * S;

    // 1) detect input dtype (0=bf16, 1=fp32)
    detect_k<<<1, 64, 0, stream>>>((const unsigned short*)h_raw, flag);

    // 2) all 7 small tensors in one convert kernel
    SmallConvArgs sca;
    sca.src[0] = mk_raw;  sca.dst[0] = mk_bf;  sca.n[0] = B * S;
    sca.src[1] = b1_raw;  sca.dst[1] = b1_bf;  sca.n[1] = F;
    sca.src[2] = b2_raw;  sca.dst[2] = b2_bf;  sca.n[2] = D;
    sca.src[3] = g1_raw;  sca.dst[3] = g1_bf;  sca.n[3] = D;
    sca.src[4] = be1_raw; sca.dst[4] = be1_bf; sca.n[4] = D;
    sca.src[5] = g2_raw;  sca.dst[5] = g2_bf;  sca.n[5] = D;
    sca.src[6] = be2_raw; sca.dst[6] = be2_bf; sca.n[6] = D;
    small_convert_k<<<dim3((B * S) / 256, 7), 256, 0, stream>>>(sca, flag);

    // 3) h: fused convert+transpose -> h_bf [B,S,D] and hT [B,D,S]
    conv_transpose_h_k<<<dim3(D / 32, S / 32, B), 256, 0, stream>>>(
        h_raw, h_bf, hT, S, D, flag);

    // 4) w1 [D,F] -> w1T [F,D]   5) w2 [F,D] -> w2T [D,F]
    conv_transpose_k<<<dim3(F / 32, D / 32), 256, 0, stream>>>(w1_raw, w1T, D, F, flag);
    conv_transpose_k<<<dim3(D / 32, F / 32), 256, 0, stream>>>(w2_raw, w2T, F, D, flag);

    // 6) scores = h @ h^T / 32   [B, S, S]   (GLL + source-pre-swizzle)
    gemm_nt<0, 1><<<dim3(S / 128, S / 128, B), 256, 0, stream>>>(
        h_bf, h_bf, scores, nullptr, S, S, D, 0.03125f, SD, SD, SS);

    // 7) softmax rows (+mask), in place
    softmax_k<<<dim3(S, B), 256, 0, stream>>>(scores, mk_bf, S);

    // 8) attn = probs @ h (via hT)  [B, S, D]   (reg variant = A/B control,
    //    same FLOP count as scores GEMM)
    gemm_nt<1, 0><<<dim3(D / 128, S / 128, B), 256, 0, stream>>>(
        scores, hT, axf, nullptr, S, D, S, 1.0f, SS, SD, SD);

    // 9) y1 = LN(h + attn)
    ln_residual_k<<<B * S, 128, 0, stream>>>(h_bf, axf, g1_bf, be1_bf, y1);

    // 10) gact = GELU(y1 @ w1 + b1)  [B*S, F]   (GLL + source-pre-swizzle)
    gemm_nt<2, 1><<<dim3(F / 128, (B * S) / 128, 1), 256, 0, stream>>>(
        y1, w1T, gact, b1_bf, B * S, F, D, 1.0f, 0, 0, 0);

    // 11) ffn = gact @ w2 + b2  [B*S, D]   (GLL + source-pre-swizzle)
    gemm_nt<3, 1><<<dim3(D / 128, (B * S) / 128, 1), 256, 0, stream>>>(
        gact, w2T, axf, b2_bf, B * S, D, F, 1.0f, 0, 0, 0);

    // 12) out = LN(y1 + ffn) -> d_out (flag-aware output dtype)
    ln_out_k<<<B * S, 128, 0, stream>>>(y1, axf, g2_bf, be2_bf, d_out, flag);
}

// Round 6
// 450.376 us; speedup vs baseline: 1.1859x; 1.0919x over previous
//
#include <hip/hip_runtime.h>
#include <hip/hip_bf16.h>
#include <math.h>

typedef __bf16 bf16;
typedef __bf16 bf16x8 __attribute__((ext_vector_type(8)));
typedef float  f32x4  __attribute__((ext_vector_type(4)));

__device__ __forceinline__ float gelu_f(float x) {
    // exact GELU: 0.5*x*(1+erf(x/sqrt(2)))
    return 0.5f * x * (1.0f + erff(x * 0.70710678118654752440f));
}

// ---------------------------------------------------------------------------
// Input-dtype detection. flag: 0 = bf16, 1 = fp32.
// ---------------------------------------------------------------------------
__global__ void detect_k(const unsigned short* __restrict__ h, int* __restrict__ flag)
{
    if (threadIdx.x == 0 && blockIdx.x == 0) {
        int cnt = 0;
        for (int i = 0; i < 256; i += 2) {
            int e = (h[i] >> 7) & 0xFF;
            cnt += (e >= 100 && e <= 140) ? 1 : 0;
        }
        *flag = (cnt >= 96) ? 0 : 1;
    }
}

// ---------------------------------------------------------------------------
// One kernel for all 7 small tensors (mask, b1, b2, g1, be1, g2, be2).
// ---------------------------------------------------------------------------
struct SmallConvArgs {
    const void* src[7];
    bf16* dst[7];
    int n[7];
};
__global__ __launch_bounds__(256) void small_convert_k(SmallConvArgs a,
                                                       const int* __restrict__ flag)
{
    const int seg = blockIdx.y;
    const int i = blockIdx.x * 256 + threadIdx.x;
    if (i >= a.n[seg]) return;
    const float v = (*flag) ? ((const float*)a.src[seg])[i]
                            : (float)((const bf16*)a.src[seg])[i];
    a.dst[seg][i] = (bf16)v;
}

// ---------------------------------------------------------------------------
// Fused convert + transpose for weights: in[R,C] (fp32 or bf16) -> outT[C,R] bf16.
// ---------------------------------------------------------------------------
__global__ __launch_bounds__(256) void conv_transpose_k(
    const void* __restrict__ in, bf16* __restrict__ outT,
    int R, int C, const int* __restrict__ flag)
{
    __shared__ bf16 tile[32][33];
    const int c0 = blockIdx.x * 32;
    const int r0 = blockIdx.y * 32;
    const int tx = threadIdx.x & 31;
    const int ty = threadIdx.x >> 5;   // 0..7
    const bool f32 = (*flag) != 0;
#pragma unroll
    for (int i = 0; i < 32; i += 8) {
        const long idx = (long)(r0 + ty + i) * C + (c0 + tx);
        const float v = f32 ? ((const float*)in)[idx] : (float)((const bf16*)in)[idx];
        tile[ty + i][tx] = (bf16)v;
    }
    __syncthreads();
#pragma unroll
    for (int i = 0; i < 32; i += 8)
        outT[(long)(c0 + ty + i) * R + (r0 + tx)] = tile[tx][ty + i];
}

// ---------------------------------------------------------------------------
// Fused convert + transpose for h: writes h_bf [B,S,D] and hT [B,D,S].
// ---------------------------------------------------------------------------
__global__ __launch_bounds__(256) void conv_transpose_h_k(
    const void* __restrict__ in, bf16* __restrict__ h_bf, bf16* __restrict__ hT,
    int S, int D, const int* __restrict__ flag)
{
    __shared__ bf16 tile[32][33];
    const long sB = (long)S * D;
    const int d0 = blockIdx.x * 32;
    const int s0 = blockIdx.y * 32;
    const int b  = blockIdx.z;
    const int tx = threadIdx.x & 31;
    const int ty = threadIdx.x >> 5;
    const bool f32 = (*flag) != 0;
#pragma unroll
    for (int i = 0; i < 32; i += 8) {
        const long idx = b * sB + (long)(s0 + ty + i) * D + (d0 + tx);
        const float v = f32 ? ((const float*)in)[idx] : (float)((const bf16*)in)[idx];
        const bf16 bv = (bf16)v;
        h_bf[idx] = bv;
        tile[ty + i][tx] = bv;
    }
    __syncthreads();
#pragma unroll
    for (int i = 0; i < 32; i += 8)
        hT[b * sB + (long)(d0 + ty + i) * S + (s0 + tx)] = tile[tx][ty + i];
}

// ---------------------------------------------------------------------------
// global_load_lds 16B: wave-uniform LDS dest + lane*16; per-lane global src.
// ---------------------------------------------------------------------------
__device__ __forceinline__ void gll16(const bf16* g, bf16* l)
{
    __builtin_amdgcn_global_load_lds(
        (const __attribute__((address_space(1))) void*)g,
        (__attribute__((address_space(3))) void*)l, 16, 0, 0);
}

// ---------------------------------------------------------------------------
// NT GEMM: C[M,N] = A[M,K] @ Bt[N,K]^T  (row-major, bf16 in/out, fp32 acc)
// 128x128 tile, BK=64, 256 threads = 4 waves (2x2), each wave 4x4 of 16x16
// MFMA tiles. Staging: GLL width-16 + source-pre-swizzle (R5-verified:
// conflicts 0, VGPR 80): lane l of an 8-row unit lands at physical chunk
// l&7 of row l>>3; it fetches logical chunk ((l&7)-(l>>3))&7 so the landed
// layout equals the (chunk+row)&7 rotate swizzle used by the readers.
//
// STAGE=1 (R5 single-buf, 608 TF = m233's 2-phase ceiling): stage -> sync
// (drains vmcnt(0), FULL latency exposed) -> compute -> sync.
// STAGE=2 (R6 dbuf, guide T3 "minimum 2-phase" recipe): FOUR SEPARATE
// static __shared__ arrays + unroll-2 so buffer identity is a distinct
// compile-time object -> LLVM alias analysis proves ds_read(As0) does not
// alias GLL-dest(As1) -> no legalizer vmcnt drain before the reads (R1's
// failure was runtime-indexed buffers). Loop: {stage next -> compute cur ->
// __syncthreads (single drain, loads aged ~1 compute phase; ~92% L2-hit so
// mostly retired)}. 64 KiB LDS -> 2 blocks/CU (self-hiding makes that ok;
// recipe proven at 1 block/CU, m248v2).
// Same-run control: attn stays STAGE=1 (all four GEMMs are 68.7 GF).
// MODE: 0 = scale (scores), 1 = plain, 2 = bias+GELU, 3 = bias
// ---------------------------------------------------------------------------
template <int MODE, int STAGE>
__global__ __launch_bounds__(256) void gemm_nt(
    const bf16* __restrict__ A, const bf16* __restrict__ Bt,
    bf16* __restrict__ C, const bf16* __restrict__ bias,
    int M, int N, int K, float scale,
    long sA, long sB, long sC)
{
    A  += (long)blockIdx.z * sA;
    Bt += (long)blockIdx.z * sB;
    C  += (long)blockIdx.z * sC;

    const int tileM = blockIdx.y * 128;
    const int tileN = blockIdx.x * 128;

    const int t    = threadIdx.x;
    const int lane = t & 63;
    const int wave = t >> 6;
    const int wr   = wave >> 1;      // wave row (0..1) -> 64-row strip
    const int wc   = wave & 1;       // wave col (0..1) -> 64-col strip
    const int quad = lane >> 4;      // 0..3
    const int l16  = lane & 15;

    const int srow   = lane >> 3;                  // staging row within unit
    const int lchunk = ((lane & 7) - srow) & 7;    // logical chunk to fetch

    f32x4 acc[4][4] = {};

    // swizzled element offset of (row, chunk): row*64 + ((chunk+row)&7)*8
    auto swz = [](int row, int chunk) { return row * 64 + (((chunk + row) & 7) * 8); };

    // stage one 128x64 K-tile (A and B) at k0 into (as, bs): 8 GLL/thread
    auto stage = [&](bf16* as, bf16* bs, int k0) {
#pragma unroll
        for (int r2 = 0; r2 < 4; ++r2) {
            const int unit = wave * 4 + r2;          // 0..15, wave-uniform
            const int row  = unit * 8 + srow;        // row&7 == srow
            const int col  = lchunk * 8;
            gll16(A  + (long)(tileM + row) * K + (k0 + col), as + unit * 512);
            gll16(Bt + (long)(tileN + row) * K + (k0 + col), bs + unit * 512);
        }
    };

    // compute one K-tile from (as, bs): 2 MFMA K-steps of 32
    auto compute = [&](const bf16* as, const bf16* bs) {
#pragma unroll
        for (int kk = 0; kk < 64; kk += 32) {
            const int chunk = (kk >> 3) + quad;
            bf16x8 af[4], bfr[4];
#pragma unroll
            for (int i = 0; i < 4; ++i) {
                af[i]  = *(const bf16x8*)&as[swz(wr * 64 + i * 16 + l16, chunk)];
                bfr[i] = *(const bf16x8*)&bs[swz(wc * 64 + i * 16 + l16, chunk)];
            }
#pragma unroll
            for (int mi = 0; mi < 4; ++mi)
#pragma unroll
                for (int ni = 0; ni < 4; ++ni)
                    acc[mi][ni] = __builtin_amdgcn_mfma_f32_16x16x32_bf16(
                        af[mi], bfr[ni], acc[mi][ni], 0, 0, 0);
        }
    };

    if constexpr (STAGE == 2) {
        // ---- double-buffered, distinct static objects (alias-provable) ----
        __shared__ __align__(16) bf16 As0[128 * 64];
        __shared__ __align__(16) bf16 As1[128 * 64];
        __shared__ __align__(16) bf16 Bs0[128 * 64];
        __shared__ __align__(16) bf16 Bs1[128 * 64];

        stage(As0, Bs0, 0);
        __syncthreads();                       // tile 0 ready
        for (int u = 0; u < K / 64; u += 2) {
            const int k1 = (u + 1) * 64;
            const int k2 = (u + 2) * 64;
            if (k1 < K) stage(As1, Bs1, k1);   // issue BEFORE compute
            compute(As0, Bs0);
            __syncthreads();                   // drain (loads aged 1 phase)
            if (k1 < K) {
                if (k2 < K) stage(As0, Bs0, k2);
                compute(As1, Bs1);
                __syncthreads();
            }
        }
    } else {
        // ---- R5 single-buffer (in-run control) ----
        __shared__ __align__(16) bf16 As[128 * 64];
        __shared__ __align__(16) bf16 Bs[128 * 64];
        for (int k0 = 0; k0 < K; k0 += 64) {
            stage(As, Bs, k0);
            __syncthreads();
            compute(As, Bs);
            __syncthreads();
        }
    }

    // ---- epilogue ----
#pragma unroll
    for (int mi = 0; mi < 4; ++mi) {
        const int rbase = tileM + wr * 64 + mi * 16 + quad * 4;
#pragma unroll
        for (int ni = 0; ni < 4; ++ni) {
            const int col = tileN + wc * 64 + ni * 16 + l16;
            float bv = 0.0f;
            if (MODE >= 2) bv = (float)bias[col];
#pragma unroll
            for (int r = 0; r < 4; ++r) {
                float v = acc[mi][ni][r];
                if (MODE == 0) v *= scale;
                if (MODE >= 2) v += bv;
                if (MODE == 2) v = gelu_f(v);
                C[(long)(rbase + r) * N + col] = (bf16)v;
            }
        }
    }
}

// ---------------------------------------------------------------------------
// Row softmax with additive mask, in place, vectorized bf16x8.
// One 256-thread block per row; S = 2048 (one bf16x8 per thread).
// ---------------------------------------------------------------------------
__global__ __launch_bounds__(256) void softmax_k(
    bf16* __restrict__ scores, const bf16* __restrict__ mask, int S)
{
    const long rowOff = ((long)blockIdx.y * S + blockIdx.x) * S;
    bf16* row = scores + rowOff;
    const bf16* mrow = mask + (long)blockIdx.y * S;
    const int t = threadIdx.x;

    const bf16x8 r = ((const bf16x8*)row)[t];
    const bf16x8 m = ((const bf16x8*)mrow)[t];
    float v[8];
    float mx = -1e30f;
#pragma unroll
    for (int i = 0; i < 8; ++i) {
        v[i] = (float)r[i] + (float)m[i];
        mx = fmaxf(mx, v[i]);
    }
#pragma unroll
    for (int off = 32; off > 0; off >>= 1)
        mx = fmaxf(mx, __shfl_down(mx, off));
    __shared__ float redm[4];
    if ((t & 63) == 0) redm[t >> 6] = mx;
    __syncthreads();
    mx = fmaxf(fmaxf(redm[0], redm[1]), fmaxf(redm[2], redm[3]));

    float s = 0.0f;
#pragma unroll
    for (int i = 0; i < 8; ++i) { v[i] = __expf(v[i] - mx); s += v[i]; }
#pragma unroll
    for (int off = 32; off > 0; off >>= 1)
        s += __shfl_down(s, off);
    __shared__ float reds[4];
    if ((t & 63) == 0) reds[t >> 6] = s;
    __syncthreads();
    s = reds[0] + reds[1] + reds[2] + reds[3];
    const float inv = 1.0f / s;
    bf16x8 o;
#pragma unroll
    for (int i = 0; i < 8; ++i) o[i] = (bf16)(v[i] * inv);
    ((bf16x8*)row)[t] = o;
}

// ---------------------------------------------------------------------------
// Fused residual + LayerNorm -> bf16 out, vectorized bf16x8.
// ---------------------------------------------------------------------------
__global__ __launch_bounds__(128) void ln_residual_k(
    const bf16* __restrict__ x1, const bf16* __restrict__ x2,
    const bf16* __restrict__ gamma, const bf16* __restrict__ beta,
    bf16* __restrict__ out)
{
    constexpr int D = 1024;
    const long off = (long)blockIdx.x * D;
    const int t = threadIdx.x;
    const bf16x8 a = ((const bf16x8*)(x1 + off))[t];
    const bf16x8 b = ((const bf16x8*)(x2 + off))[t];
    float v[8];
    float s = 0.0f, s2 = 0.0f;
#pragma unroll
    for (int i = 0; i < 8; ++i) {
        v[i] = (float)a[i] + (float)b[i];
        s  += v[i];
        s2 += v[i] * v[i];
    }
#pragma unroll
    for (int o2 = 32; o2 > 0; o2 >>= 1) {
        s  += __shfl_down(s, o2);
        s2 += __shfl_down(s2, o2);
    }
    __shared__ float rs[2], rs2[2];
    if ((t & 63) == 0) { rs[t >> 6] = s; rs2[t >> 6] = s2; }
    __syncthreads();
    s  = rs[0] + rs[1];
    s2 = rs2[0] + rs2[1];
    const float mean = s / (float)D;
    const float var  = s2 / (float)D - mean * mean;
    const float inv  = rsqrtf(var + 1e-5f);
    const bf16x8 g  = ((const bf16x8*)gamma)[t];
    const bf16x8 be = ((const bf16x8*)beta)[t];
    bf16x8 o;
#pragma unroll
    for (int i = 0; i < 8; ++i)
        o[i] = (bf16)((v[i] - mean) * inv * (float)g[i] + (float)be[i]);
    ((bf16x8*)(out + off))[t] = o;
}

// ---------------------------------------------------------------------------
// Final residual + LayerNorm -> d_out with flag-aware store dtype.
// ---------------------------------------------------------------------------
__global__ __launch_bounds__(128) void ln_out_k(
    const bf16* __restrict__ x1, const bf16* __restrict__ x2,
    const bf16* __restrict__ gamma, const bf16* __restrict__ beta,
    void* __restrict__ outv, const int* __restrict__ flag)
{
    constexpr int D = 1024;
    const long off = (long)blockIdx.x * D;
    const int t = threadIdx.x;
    const bf16x8 a = ((const bf16x8*)(x1 + off))[t];
    const bf16x8 b = ((const bf16x8*)(x2 + off))[t];
    float v[8];
    float s = 0.0f, s2 = 0.0f;
#pragma unroll
    for (int i = 0; i < 8; ++i) {
        v[i] = (float)a[i] + (float)b[i];
        s  += v[i];
        s2 += v[i] * v[i];
    }
#pragma unroll
    for (int o2 = 32; o2 > 0; o2 >>= 1) {
        s  += __shfl_down(s, o2);
        s2 += __shfl_down(s2, o2);
    }
    __shared__ float rs[2], rs2[2];
    if ((t & 63) == 0) { rs[t >> 6] = s; rs2[t >> 6] = s2; }
    __syncthreads();
    s  = rs[0] + rs[1];
    s2 = rs2[0] + rs2[1];
    const float mean = s / (float)D;
    const float var  = s2 / (float)D - mean * mean;
    const float inv  = rsqrtf(var + 1e-5f);
    const bf16x8 g  = ((const bf16x8*)gamma)[t];
    const bf16x8 be = ((const bf16x8*)beta)[t];
    if (*flag) {
        f32x4 o1, o2v;
#pragma unroll
        for (int i = 0; i < 4; ++i) {
            o1[i]  = (v[i] - mean) * inv * (float)g[i] + (float)be[i];
            o2v[i] = (v[4 + i] - mean) * inv * (float)g[4 + i] + (float)be[4 + i];
        }
        f32x4* op = (f32x4*)((float*)outv + off);
        op[t * 2]     = o1;
        op[t * 2 + 1] = o2v;
    } else {
        bf16x8 o;
#pragma unroll
        for (int i = 0; i < 8; ++i)
            o[i] = (bf16)((v[i] - mean) * inv * (float)g[i] + (float)be[i]);
        ((bf16x8*)((bf16*)outv + off))[t] = o;
    }
}

// ---------------------------------------------------------------------------
extern "C" void kernel_launch(void* const* d_in, const int* in_sizes, int n_in,
                              void* d_out, int out_size, void* d_ws, size_t ws_size,
                              hipStream_t stream)
{
    constexpr int B = 4, S = 2048, D = 1024, F = 4096;
    constexpr long MB = 1024 * 1024;

    const void* h_raw  = d_in[0];
    const void* mk_raw = d_in[1];
    const void* w1_raw = d_in[2];
    const void* b1_raw = d_in[3];
    const void* w2_raw = d_in[4];
    const void* b2_raw = d_in[5];
    const void* g1_raw = d_in[6];
    const void* be1_raw= d_in[7];
    const void* g2_raw = d_in[8];
    const void* be2_raw= d_in[9];

    // ws layout (liveness-checked overlays), 112 MiB + small tail:
    char* ws = (char*)d_ws;
    bf16* scores = (bf16*)(ws + 0);
    bf16* gact   = (bf16*)(ws + 0);
    bf16* hT     = (bf16*)(ws + 32 * MB);
    bf16* h_bf   = (bf16*)(ws + 48 * MB);
    bf16* y1     = (bf16*)(ws + 64 * MB);
    bf16* w1T    = (bf16*)(ws + 80 * MB);
    bf16* w2T    = (bf16*)(ws + 88 * MB);
    bf16* axf    = (bf16*)(ws + 96 * MB);    // attn, later ffn
    char* sm     = ws + 112 * MB;
    int*  flag   = (int*)(sm);
    bf16* mk_bf  = (bf16*)(sm + 1024);
    bf16* b1_bf  = (bf16*)(sm + 17408 + 1024);
    bf16* b2_bf  = (bf16*)(sm + 25600 + 3072);
    bf16* g1_bf  = (bf16*)(sm + 27648 + 3072);
    bf16* be1_bf = (bf16*)(sm + 29696 + 3072);
    bf16* g2_bf  = (bf16*)(sm + 31744 + 3072);
    bf16* be2_bf = (bf16*)(sm + 33792 + 3072);

    const long SD = (long)S * D;
    const long SS = (long)S * S;

    // 1) detect input dtype (0=bf16, 1=fp32)
    detect_k<<<1, 64, 0, stream>>>((const unsigned short*)h_raw, flag);

    // 2) all 7 small tensors in one convert kernel
    SmallConvArgs sca;
    sca.src[0] = mk_raw;  sca.dst[0] = mk_bf;  sca.n[0] = B * S;
    sca.src[1] = b1_raw;  sca.dst[1] = b1_bf;  sca.n[1] = F;
    sca.src[2] = b2_raw;  sca.dst[2] = b2_bf;  sca.n[2] = D;
    sca.src[3] = g1_raw;  sca.dst[3] = g1_bf;  sca.n[3] = D;
    sca.src[4] = be1_raw; sca.dst[4] = be1_bf; sca.n[4] = D;
    sca.src[5] = g2_raw;  sca.dst[5] = g2_bf;  sca.n[5] = D;
    sca.src[6] = be2_raw; sca.dst[6] = be2_bf; sca.n[6] = D;
    small_convert_k<<<dim3((B * S) / 256, 7), 256, 0, stream>>>(sca, flag);

    // 3) h: fused convert+transpose -> h_bf [B,S,D] and hT [B,D,S]
    conv_transpose_h_k<<<dim3(D / 32, S / 32, B), 256, 0, stream>>>(
        h_raw, h_bf, hT, S, D, flag);

    // 4) w1 [D,F] -> w1T [F,D]   5) w2 [F,D] -> w2T [D,F]
    conv_transpose_k<<<dim3(F / 32, D / 32), 256, 0, stream>>>(w1_raw, w1T, D, F, flag);
    conv_transpose_k<<<dim3(D / 32, F / 32), 256, 0, stream>>>(w2_raw, w2T, F, D, flag);

    // 6) scores = h @ h^T / 32   [B, S, S]   (dbuf)
    gemm_nt<0, 2><<<dim3(S / 128, S / 128, B), 256, 0, stream>>>(
        h_bf, h_bf, scores, nullptr, S, S, D, 0.03125f, SD, SD, SS);

    // 7) softmax rows (+mask), in place
    softmax_k<<<dim3(S, B), 256, 0, stream>>>(scores, mk_bf, S);

    // 8) attn = probs @ h (via hT)  [B, S, D]   (single-buf = in-run control,
    //    same 68.7 GF as every other GEMM)
    gemm_nt<1, 1><<<dim3(D / 128, S / 128, B), 256, 0, stream>>>(
        scores, hT, axf, nullptr, S, D, S, 1.0f, SS, SD, SD);

    // 9) y1 = LN(h + attn)
    ln_residual_k<<<B * S, 128, 0, stream>>>(h_bf, axf, g1_bf, be1_bf, y1);

    // 10) gact = GELU(y1 @ w1 + b1)  [B*S, F]   (dbuf)
    gemm_nt<2, 2><<<dim3(F / 128, (B * S) / 128, 1), 256, 0, stream>>>(
        y1, w1T, gact, b1_bf, B * S, F, D, 1.0f, 0, 0, 0);

    // 11) ffn = gact @ w2 + b2  [B*S, D]   (dbuf)
    gemm_nt<3, 2><<<dim3(D / 128, (B * S) / 128, 1), 256, 0, stream>>>(
        gact, w2T, axf, b2_bf, B * S, D, F, 1.0f, 0, 0, 0);

    // 12) out = LN(y1 + ffn) -> d_out (flag-aware output dtype)
    ln_out_k<<<B * S, 128, 0, stream>>>(y1, axf, g2_bf, be2_bf, d_out, flag);
}

// Round 7
// 443.136 us; speedup vs baseline: 1.2053x; 1.0163x over previous
//
#include <hip/hip_runtime.h>
#include <hip/hip_bf16.h>
#include <math.h>

typedef __bf16 bf16;
typedef __bf16 bf16x8 __attribute__((ext_vector_type(8)));
typedef float  f32x4  __attribute__((ext_vector_type(4)));

__device__ __forceinline__ float gelu_f(float x) {
    // exact GELU: 0.5*x*(1+erf(x/sqrt(2)))
    return 0.5f * x * (1.0f + erff(x * 0.70710678118654752440f));
}

// ---------------------------------------------------------------------------
// Input-dtype detection. flag: 0 = bf16, 1 = fp32.
// ---------------------------------------------------------------------------
__global__ void detect_k(const unsigned short* __restrict__ h, int* __restrict__ flag)
{
    if (threadIdx.x == 0 && blockIdx.x == 0) {
        int cnt = 0;
        for (int i = 0; i < 256; i += 2) {
            int e = (h[i] >> 7) & 0xFF;
            cnt += (e >= 100 && e <= 140) ? 1 : 0;
        }
        *flag = (cnt >= 96) ? 0 : 1;
    }
}

// ---------------------------------------------------------------------------
// One kernel for all 7 small tensors (mask, b1, b2, g1, be1, g2, be2).
// ---------------------------------------------------------------------------
struct SmallConvArgs {
    const void* src[7];
    bf16* dst[7];
    int n[7];
};
__global__ __launch_bounds__(256) void small_convert_k(SmallConvArgs a,
                                                       const int* __restrict__ flag)
{
    const int seg = blockIdx.y;
    const int i = blockIdx.x * 256 + threadIdx.x;
    if (i >= a.n[seg]) return;
    const float v = (*flag) ? ((const float*)a.src[seg])[i]
                            : (float)((const bf16*)a.src[seg])[i];
    a.dst[seg][i] = (bf16)v;
}

// ---------------------------------------------------------------------------
// Fused convert + transpose for weights: in[R,C] (fp32 or bf16) -> outT[C,R] bf16.
// ---------------------------------------------------------------------------
__global__ __launch_bounds__(256) void conv_transpose_k(
    const void* __restrict__ in, bf16* __restrict__ outT,
    int R, int C, const int* __restrict__ flag)
{
    __shared__ bf16 tile[32][33];
    const int c0 = blockIdx.x * 32;
    const int r0 = blockIdx.y * 32;
    const int tx = threadIdx.x & 31;
    const int ty = threadIdx.x >> 5;   // 0..7
    const bool f32 = (*flag) != 0;
#pragma unroll
    for (int i = 0; i < 32; i += 8) {
        const long idx = (long)(r0 + ty + i) * C + (c0 + tx);
        const float v = f32 ? ((const float*)in)[idx] : (float)((const bf16*)in)[idx];
        tile[ty + i][tx] = (bf16)v;
    }
    __syncthreads();
#pragma unroll
    for (int i = 0; i < 32; i += 8)
        outT[(long)(c0 + ty + i) * R + (r0 + tx)] = tile[tx][ty + i];
}

// ---------------------------------------------------------------------------
// Fused convert + transpose for h: writes h_bf [B,S,D] and hT [B,D,S].
// ---------------------------------------------------------------------------
__global__ __launch_bounds__(256) void conv_transpose_h_k(
    const void* __restrict__ in, bf16* __restrict__ h_bf, bf16* __restrict__ hT,
    int S, int D, const int* __restrict__ flag)
{
    __shared__ bf16 tile[32][33];
    const long sB = (long)S * D;
    const int d0 = blockIdx.x * 32;
    const int s0 = blockIdx.y * 32;
    const int b  = blockIdx.z;
    const int tx = threadIdx.x & 31;
    const int ty = threadIdx.x >> 5;
    const bool f32 = (*flag) != 0;
#pragma unroll
    for (int i = 0; i < 32; i += 8) {
        const long idx = b * sB + (long)(s0 + ty + i) * D + (d0 + tx);
        const float v = f32 ? ((const float*)in)[idx] : (float)((const bf16*)in)[idx];
        const bf16 bv = (bf16)v;
        h_bf[idx] = bv;
        tile[ty + i][tx] = bv;
    }
    __syncthreads();
#pragma unroll
    for (int i = 0; i < 32; i += 8)
        hT[b * sB + (long)(d0 + ty + i) * S + (s0 + tx)] = tile[tx][ty + i];
}

// ---------------------------------------------------------------------------
// global_load_lds 16B: wave-uniform LDS dest + lane*16; per-lane global src.
// ---------------------------------------------------------------------------
__device__ __forceinline__ void gll16(const bf16* g, bf16* l)
{
    __builtin_amdgcn_global_load_lds(
        (const __attribute__((address_space(1))) void*)g,
        (__attribute__((address_space(3))) void*)l, 16, 0, 0);
}

// ---------------------------------------------------------------------------
// NT GEMM, big-tile: C[M,N] = A[M,K] @ Bt[N,K]^T  (bf16 in/out, fp32 acc)
// R7: BMxBN tile (256x256 or 256x128), BK=64, 512 threads = 8 waves (2x4);
// per-wave output (BM/2)x(BN/4). Rationale: the 128^2/BK64/2-phase family is
// exhausted at ~600 TF (R5 single=608, R6 dbuf=583, R1/R2 phase-games worse;
// = m233's measured 2-phase ceiling). The un-tried axis is tile size: m230
// 256^2+2ph = 682 TF (+12% over 128^2+2ph) via 2x arithmetic intensity
// (half the staged bytes per FLOP, MFMA:ds_read 2.7:1 vs 2:1).
// Composition of session-verified parts ONLY:
//  - GLL width-16 + source-pre-swizzle (R5: conflicts 0): lane l of an
//    8-row unit lands at physical chunk l&7 of row l>>3; fetches logical
//    chunk ((l&7)-(l>>3))&7 == landed layout equals (chunk+row)&7 rotate.
//  - 8-wave 2x4 layout + 512-thread staging (R1/R2: ran correct twice).
//  - dbuf-issue-early loop with 4 distinct static __shared__ arrays
//    (R6: correct; at 1 block/CU it is the only latency-hiding mechanism).
// LDS: 256x256 -> 128 KiB, 256x128 -> 96 KiB => 1 block/CU.
// __launch_bounds__(512,2) caps VGPR at 256 (acc 128 + frags ~60 -> ~190).
// Requires M%BM==0, N%BN==0, K%128==0 (all shapes here satisfy).
// MODE: 0 = scale (scores), 1 = plain, 2 = bias+GELU, 3 = bias
// ---------------------------------------------------------------------------
template <int MODE, int BM, int BN>
__global__ __launch_bounds__(512, 2) void gemm_big(
    const bf16* __restrict__ A, const bf16* __restrict__ Bt,
    bf16* __restrict__ C, const bf16* __restrict__ bias,
    int M, int N, int K, float scale,
    long sA, long sB, long sC)
{
    constexpr int WM = BM / 2;       // per-wave rows
    constexpr int WN = BN / 4;       // per-wave cols
    constexpr int MI = WM / 16;      // 16-row fragments per wave
    constexpr int NI = WN / 16;      // 16-col fragments per wave

    A  += (long)blockIdx.z * sA;
    Bt += (long)blockIdx.z * sB;
    C  += (long)blockIdx.z * sC;

    const int tileM = blockIdx.y * BM;
    const int tileN = blockIdx.x * BN;

    // four distinct static objects: alias-provable dbuf (R6 pattern)
    __shared__ __align__(16) bf16 As0[BM * 64];
    __shared__ __align__(16) bf16 As1[BM * 64];
    __shared__ __align__(16) bf16 Bs0[BN * 64];
    __shared__ __align__(16) bf16 Bs1[BN * 64];

    const int t    = threadIdx.x;
    const int lane = t & 63;
    const int wave = t >> 6;         // 0..7
    const int wr   = wave >> 2;      // 0..1 -> WM-row strip
    const int wc   = wave & 3;       // 0..3 -> WN-col strip
    const int quad = lane >> 4;      // 0..3
    const int l16  = lane & 15;

    const int srow   = lane >> 3;                  // staging row within unit
    const int lchunk = ((lane & 7) - srow) & 7;    // logical chunk to fetch

    f32x4 acc[MI][NI] = {};

    // swizzled element offset of (row, chunk): row*64 + ((chunk+row)&7)*8
    auto swz = [](int row, int chunk) { return row * 64 + (((chunk + row) & 7) * 8); };

    // stage one BMx64 A-tile + BNx64 B-tile at k0: one GLL per 8-row unit
    auto stage = [&](bf16* as, bf16* bs, int k0) {
#pragma unroll
        for (int r2 = 0; r2 < BM / 64; ++r2) {
            const int unit = wave * (BM / 64) + r2;      // wave-uniform
            const int row  = unit * 8 + srow;            // row&7 == srow
            gll16(A + (long)(tileM + row) * K + (k0 + lchunk * 8), as + unit * 512);
        }
#pragma unroll
        for (int r2 = 0; r2 < BN / 64; ++r2) {
            const int unit = wave * (BN / 64) + r2;
            const int row  = unit * 8 + srow;
            gll16(Bt + (long)(tileN + row) * K + (k0 + lchunk * 8), bs + unit * 512);
        }
    };

    // compute one K-tile: 2 MFMA K-steps of 32, MI x NI fragments
    auto compute = [&](const bf16* as, const bf16* bs) {
#pragma unroll
        for (int kk = 0; kk < 64; kk += 32) {
            const int chunk = (kk >> 3) + quad;
            bf16x8 af[MI], bfr[NI];
#pragma unroll
            for (int i = 0; i < MI; ++i)
                af[i] = *(const bf16x8*)&as[swz(wr * WM + i * 16 + l16, chunk)];
#pragma unroll
            for (int j = 0; j < NI; ++j)
                bfr[j] = *(const bf16x8*)&bs[swz(wc * WN + j * 16 + l16, chunk)];
#pragma unroll
            for (int mi = 0; mi < MI; ++mi)
#pragma unroll
                for (int ni = 0; ni < NI; ++ni)
                    acc[mi][ni] = __builtin_amdgcn_mfma_f32_16x16x32_bf16(
                        af[mi], bfr[ni], acc[mi][ni], 0, 0, 0);
        }
    };

    stage(As0, Bs0, 0);
    __syncthreads();                       // tile 0 ready
    for (int u = 0; u < K / 64; u += 2) {
        const int k1 = (u + 1) * 64;
        const int k2 = (u + 2) * 64;
        if (k1 < K) stage(As1, Bs1, k1);   // issue BEFORE compute
        compute(As0, Bs0);
        __syncthreads();
        if (k1 < K) {
            if (k2 < K) stage(As0, Bs0, k2);
            compute(As1, Bs1);
            __syncthreads();
        }
    }

    // ---- epilogue ----
#pragma unroll
    for (int mi = 0; mi < MI; ++mi) {
        const int rbase = tileM + wr * WM + mi * 16 + quad * 4;
#pragma unroll
        for (int ni = 0; ni < NI; ++ni) {
            const int col = tileN + wc * WN + ni * 16 + l16;
            float bv = 0.0f;
            if (MODE >= 2) bv = (float)bias[col];
#pragma unroll
            for (int r = 0; r < 4; ++r) {
                float v = acc[mi][ni][r];
                if (MODE == 0) v *= scale;
                if (MODE >= 2) v += bv;
                if (MODE == 2) v = gelu_f(v);
                C[(long)(rbase + r) * N + col] = (bf16)v;
            }
        }
    }
}

// ---------------------------------------------------------------------------
// Row softmax with additive mask, in place, vectorized bf16x8.
// One 256-thread block per row; S = 2048 (one bf16x8 per thread).
// ---------------------------------------------------------------------------
__global__ __launch_bounds__(256) void softmax_k(
    bf16* __restrict__ scores, const bf16* __restrict__ mask, int S)
{
    const long rowOff = ((long)blockIdx.y * S + blockIdx.x) * S;
    bf16* row = scores + rowOff;
    const bf16* mrow = mask + (long)blockIdx.y * S;
    const int t = threadIdx.x;

    const bf16x8 r = ((const bf16x8*)row)[t];
    const bf16x8 m = ((const bf16x8*)mrow)[t];
    float v[8];
    float mx = -1e30f;
#pragma unroll
    for (int i = 0; i < 8; ++i) {
        v[i] = (float)r[i] + (float)m[i];
        mx = fmaxf(mx, v[i]);
    }
#pragma unroll
    for (int off = 32; off > 0; off >>= 1)
        mx = fmaxf(mx, __shfl_down(mx, off));
    __shared__ float redm[4];
    if ((t & 63) == 0) redm[t >> 6] = mx;
    __syncthreads();
    mx = fmaxf(fmaxf(redm[0], redm[1]), fmaxf(redm[2], redm[3]));

    float s = 0.0f;
#pragma unroll
    for (int i = 0; i < 8; ++i) { v[i] = __expf(v[i] - mx); s += v[i]; }
#pragma unroll
    for (int off = 32; off > 0; off >>= 1)
        s += __shfl_down(s, off);
    __shared__ float reds[4];
    if ((t & 63) == 0) reds[t >> 6] = s;
    __syncthreads();
    s = reds[0] + reds[1] + reds[2] + reds[3];
    const float inv = 1.0f / s;
    bf16x8 o;
#pragma unroll
    for (int i = 0; i < 8; ++i) o[i] = (bf16)(v[i] * inv);
    ((bf16x8*)row)[t] = o;
}

// ---------------------------------------------------------------------------
// Fused residual + LayerNorm -> bf16 out, vectorized bf16x8.
// ---------------------------------------------------------------------------
__global__ __launch_bounds__(128) void ln_residual_k(
    const bf16* __restrict__ x1, const bf16* __restrict__ x2,
    const bf16* __restrict__ gamma, const bf16* __restrict__ beta,
    bf16* __restrict__ out)
{
    constexpr int D = 1024;
    const long off = (long)blockIdx.x * D;
    const int t = threadIdx.x;
    const bf16x8 a = ((const bf16x8*)(x1 + off))[t];
    const bf16x8 b = ((const bf16x8*)(x2 + off))[t];
    float v[8];
    float s = 0.0f, s2 = 0.0f;
#pragma unroll
    for (int i = 0; i < 8; ++i) {
        v[i] = (float)a[i] + (float)b[i];
        s  += v[i];
        s2 += v[i] * v[i];
    }
#pragma unroll
    for (int o2 = 32; o2 > 0; o2 >>= 1) {
        s  += __shfl_down(s, o2);
        s2 += __shfl_down(s2, o2);
    }
    __shared__ float rs[2], rs2[2];
    if ((t & 63) == 0) { rs[t >> 6] = s; rs2[t >> 6] = s2; }
    __syncthreads();
    s  = rs[0] + rs[1];
    s2 = rs2[0] + rs2[1];
    const float mean = s / (float)D;
    const float var  = s2 / (float)D - mean * mean;
    const float inv  = rsqrtf(var + 1e-5f);
    const bf16x8 g  = ((const bf16x8*)gamma)[t];
    const bf16x8 be = ((const bf16x8*)beta)[t];
    bf16x8 o;
#pragma unroll
    for (int i = 0; i < 8; ++i)
        o[i] = (bf16)((v[i] - mean) * inv * (float)g[i] + (float)be[i]);
    ((bf16x8*)(out + off))[t] = o;
}

// ---------------------------------------------------------------------------
// Final residual + LayerNorm -> d_out with flag-aware store dtype.
// ---------------------------------------------------------------------------
__global__ __launch_bounds__(128) void ln_out_k(
    const bf16* __restrict__ x1, const bf16* __restrict__ x2,
    const bf16* __restrict__ gamma, const bf16* __restrict__ beta,
    void* __restrict__ outv, const int* __restrict__ flag)
{
    constexpr int D = 1024;
    const long off = (long)blockIdx.x * D;
    const int t = threadIdx.x;
    const bf16x8 a = ((const bf16x8*)(x1 + off))[t];
    const bf16x8 b = ((const bf16x8*)(x2 + off))[t];
    float v[8];
    float s = 0.0f, s2 = 0.0f;
#pragma unroll
    for (int i = 0; i < 8; ++i) {
        v[i] = (float)a[i] + (float)b[i];
        s  += v[i];
        s2 += v[i] * v[i];
    }
#pragma unroll
    for (int o2 = 32; o2 > 0; o2 >>= 1) {
        s  += __shfl_down(s, o2);
        s2 += __shfl_down(s2, o2);
    }
    __shared__ float rs[2], rs2[2];
    if ((t & 63) == 0) { rs[t >> 6] = s; rs2[t >> 6] = s2; }
    __syncthreads();
    s  = rs[0] + rs[1];
    s2 = rs2[0] + rs2[1];
    const float mean = s / (float)D;
    const float var  = s2 / (float)D - mean * mean;
    const float inv  = rsqrtf(var + 1e-5f);
    const bf16x8 g  = ((const bf16x8*)gamma)[t];
    const bf16x8 be = ((const bf16x8*)beta)[t];
    if (*flag) {
        f32x4 o1, o2v;
#pragma unroll
        for (int i = 0; i < 4; ++i) {
            o1[i]  = (v[i] - mean) * inv * (float)g[i] + (float)be[i];
            o2v[i] = (v[4 + i] - mean) * inv * (float)g[4 + i] + (float)be[4 + i];
        }
        f32x4* op = (f32x4*)((float*)outv + off);
        op[t * 2]     = o1;
        op[t * 2 + 1] = o2v;
    } else {
        bf16x8 o;
#pragma unroll
        for (int i = 0; i < 8; ++i)
            o[i] = (bf16)((v[i] - mean) * inv * (float)g[i] + (float)be[i]);
        ((bf16x8*)((bf16*)outv + off))[t] = o;
    }
}

// ---------------------------------------------------------------------------
extern "C" void kernel_launch(void* const* d_in, const int* in_sizes, int n_in,
                              void* d_out, int out_size, void* d_ws, size_t ws_size,
                              hipStream_t stream)
{
    constexpr int B = 4, S = 2048, D = 1024, F = 4096;
    constexpr long MB = 1024 * 1024;

    const void* h_raw  = d_in[0];
    const void* mk_raw = d_in[1];
    const void* w1_raw = d_in[2];
    const void* b1_raw = d_in[3];
    const void* w2_raw = d_in[4];
    const void* b2_raw = d_in[5];
    const void* g1_raw = d_in[6];
    const void* be1_raw= d_in[7];
    const void* g2_raw = d_in[8];
    const void* be2_raw= d_in[9];

    // ws layout (liveness-checked overlays), 112 MiB + small tail:
    char* ws = (char*)d_ws;
    bf16* scores = (bf16*)(ws + 0);
    bf16* gact   = (bf16*)(ws + 0);
    bf16* hT     = (bf16*)(ws + 32 * MB);
    bf16* h_bf   = (bf16*)(ws + 48 * MB);
    bf16* y1     = (bf16*)(ws + 64 * MB);
    bf16* w1T    = (bf16*)(ws + 80 * MB);
    bf16* w2T    = (bf16*)(ws + 88 * MB);
    bf16* axf    = (bf16*)(ws + 96 * MB);    // attn, later ffn
    char* sm     = ws + 112 * MB;
    int*  flag   = (int*)(sm);
    bf16* mk_bf  = (bf16*)(sm + 1024);
    bf16* b1_bf  = (bf16*)(sm + 17408 + 1024);
    bf16* b2_bf  = (bf16*)(sm + 25600 + 3072);
    bf16* g1_bf  = (bf16*)(sm + 27648 + 3072);
    bf16* be1_bf = (bf16*)(sm + 29696 + 3072);
    bf16* g2_bf  = (bf16*)(sm + 31744 + 3072);
    bf16* be2_bf = (bf16*)(sm + 33792 + 3072);

    const long SD = (long)S * D;
    const long SS = (long)S * S;

    // 1) detect input dtype (0=bf16, 1=fp32)
    detect_k<<<1, 64, 0, stream>>>((const unsigned short*)h_raw, flag);

    // 2) all 7 small tensors in one convert kernel
    SmallConvArgs sca;
    sca.src[0] = mk_raw;  sca.dst[0] = mk_bf;  sca.n[0] = B * S;
    sca.src[1] = b1_raw;  sca.dst[1] = b1_bf;  sca.n[1] = F;
    sca.src[2] = b2_raw;  sca.dst[2] = b2_bf;  sca.n[2] = D;
    sca.src[3] = g1_raw;  sca.dst[3] = g1_bf;  sca.n[3] = D;
    sca.src[4] = be1_raw; sca.dst[4] = be1_bf; sca.n[4] = D;
    sca.src[5] = g2_raw;  sca.dst[5] = g2_bf;  sca.n[5] = D;
    sca.src[6] = be2_raw; sca.dst[6] = be2_bf; sca.n[6] = D;
    small_convert_k<<<dim3((B * S) / 256, 7), 256, 0, stream>>>(sca, flag);

    // 3) h: fused convert+transpose -> h_bf [B,S,D] and hT [B,D,S]
    conv_transpose_h_k<<<dim3(D / 32, S / 32, B), 256, 0, stream>>>(
        h_raw, h_bf, hT, S, D, flag);

    // 4) w1 [D,F] -> w1T [F,D]   5) w2 [F,D] -> w2T [D,F]
    conv_transpose_k<<<dim3(F / 32, D / 32), 256, 0, stream>>>(w1_raw, w1T, D, F, flag);
    conv_transpose_k<<<dim3(D / 32, F / 32), 256, 0, stream>>>(w2_raw, w2T, F, D, flag);

    // 6) scores = h @ h^T / 32   [B, S, S]   (256x256, 256 blocks)
    gemm_big<0, 256, 256><<<dim3(S / 256, S / 256, B), 512, 0, stream>>>(
        h_bf, h_bf, scores, nullptr, S, S, D, 0.03125f, SD, SD, SS);

    // 7) softmax rows (+mask), in place
    softmax_k<<<dim3(S, B), 256, 0, stream>>>(scores, mk_bf, S);

    // 8) attn = probs @ h (via hT)  [B, S, D]   (256x128, 256 blocks)
    gemm_big<1, 256, 128><<<dim3(D / 128, S / 256, B), 512, 0, stream>>>(
        scores, hT, axf, nullptr, S, D, S, 1.0f, SS, SD, SD);

    // 9) y1 = LN(h + attn)
    ln_residual_k<<<B * S, 128, 0, stream>>>(h_bf, axf, g1_bf, be1_bf, y1);

    // 10) gact = GELU(y1 @ w1 + b1)  [B*S, F]   (256x256, 512 blocks)
    gemm_big<2, 256, 256><<<dim3(F / 256, (B * S) / 256, 1), 512, 0, stream>>>(
        y1, w1T, gact, b1_bf, B * S, F, D, 1.0f, 0, 0, 0);

    // 11) ffn = gact @ w2 + b2  [B*S, D]   (256x128, 256 blocks)
    gemm_big<3, 256, 128><<<dim3(D / 128, (B * S) / 256, 1), 512, 0, stream>>>(
        gact, w2T, axf, b2_bf, B * S, D, F, 1.0f, 0, 0, 0);

    // 12) out = LN(y1 + ffn) -> d_out (flag-aware output dtype)
    ln_out_k<<<B * S, 128, 0, stream>>>(y1, axf, g2_bf, be2_bf, d_out, flag);
}